// Round 5
// baseline (1148.371 us; speedup 1.0000x reference)
//
#include <hip/hip_runtime.h>
#include <hip/hip_bf16.h>

typedef __hip_bfloat16 bf16;
typedef float          f32x4 __attribute__((ext_vector_type(4)));
typedef unsigned short u16x4 __attribute__((ext_vector_type(4)));

#define N_NODES  100000
#define EMBED    64
#define N_EDGES  3200000
#define ND       6400000
#define N_LAYERS 3

// bucketed CSR build
#define PNB  256            // number of dst buckets
#define BSZ  391            // nodes per bucket (256*391 = 100096 >= N_NODES)
#define EPB  4096           // edges per partition block
#define NSL  8              // src slices (L2 locality)
#define SLW  12512          // slice width: 8*12512 = 100096 >= N_NODES
#define R8   (BSZ * NSL)    // 3128 per-bucket (row,slice) bins

// persistent spmm
#define SROWS 25            // rows per wave; 1024 blk * 4 waves * 25 = 102400
#define SGRID 1024          // co-resident at >=4 blocks/CU

// flags: [0] edge_nz  [1] emb_outl

__global__ void k_flags0(int* f, int* bcnt) {
    int t = threadIdx.x;
    if (t < 16) f[t] = 0;
    bcnt[t] = 0;
}

// int64 [2,E] viewed as i32 words: odd words (high halves) all zero.
__global__ void k_scan_edge(const int* __restrict__ edge, int* __restrict__ fl) {
    long long step = (long long)gridDim.x * blockDim.x;
    int found = 0;
    for (long long j = (long long)blockIdx.x * blockDim.x + threadIdx.x;
         j < N_EDGES; j += step)
        if (edge[2 * j + 1] != 0) found = 1;
    if (found) atomicOr(&fl[0], 1);
}

// bf16 census (safety; expected fp32)
__global__ void k_scan_emb(const unsigned short* __restrict__ u, int* __restrict__ fl) {
    long long step = (long long)gridDim.x * blockDim.x;
    int local = 0;
    for (long long j = (long long)blockIdx.x * blockDim.x + threadIdx.x;
         j < ND; j += step) {
        unsigned b = (u[j] >> 8) & 0x7f;
        if (b < 0x2e || b > 0x41) local++;
    }
    if (local) atomicAdd(&fl[1], local);
}

__device__ __forceinline__ int is_i64(const int* fl) { return fl[0] == 0; }
__device__ __forceinline__ int rd_src(const int* e, int i64, int k) {
    return i64 ? e[2 * k] : e[k];
}
__device__ __forceinline__ int rd_dst(const int* e, int i64, int k) {
    return i64 ? e[2 * (N_EDGES + k)] : e[N_EDGES + k];
}
__device__ __forceinline__ int clampid(int v) {
    return (v < 0) ? 0 : ((v >= N_NODES) ? (N_NODES - 1) : v);
}
__device__ __forceinline__ float rd_emb(const void* emb, const int* fl, int i) {
    if (fl[1] < (ND / 16)) return __bfloat162float(((const bf16*)emb)[i]);
    return ((const float*)emb)[i];
}

// ---- coarse bucket counts (LDS hist, 256 bins) ----
__global__ void __launch_bounds__(256) k_bcnt(const int* __restrict__ edge,
                                              const int* __restrict__ fl,
                                              int* __restrict__ bcnt) {
    __shared__ int h[PNB];
    int t = threadIdx.x;
    h[t] = 0;
    __syncthreads();
    int i64 = is_i64(fl);
    int step = gridDim.x * 256;
    for (int e = blockIdx.x * 256 + t; e < N_EDGES; e += step) {
        int d = clampid(rd_dst(edge, i64, e));
        atomicAdd(&h[d / BSZ], 1);
    }
    __syncthreads();
    if (h[t]) atomicAdd(&bcnt[t], h[t]);
}

// ---- parallel exclusive scan of bucket counts (1 block) ----
__global__ void __launch_bounds__(256) k_bscan(const int* __restrict__ bcnt,
                                               int* __restrict__ bbase,
                                               int* __restrict__ bcur) {
    __shared__ int sb[PNB];
    int t = threadIdx.x;
    int c = bcnt[t];
    sb[t] = c;
    __syncthreads();
    for (int off = 1; off < PNB; off <<= 1) {
        int v = (t >= off) ? sb[t - off] : 0;
        __syncthreads();
        sb[t] += v;
        __syncthreads();
    }
    int ex = sb[t] - c;
    bbase[t] = ex;
    bcur[t] = ex;
    if (t == PNB - 1) bbase[PNB] = sb[t];
}

// ---- partition edges into dst-buckets, LDS counting sort per 4096-edge block ----
__global__ void __launch_bounds__(256) k_part(const int* __restrict__ edge,
                                              const int* __restrict__ fl,
                                              int* __restrict__ bcur,
                                              uint2* __restrict__ pairs) {
    __shared__ int h[PNB];
    __shared__ int excl[PNB];
    __shared__ int gbase[PNB];
    __shared__ int lcur[PNB];
    __shared__ uint2 st[EPB];
    __shared__ unsigned char binof[EPB];
    int t = threadIdx.x;
    int e0 = blockIdx.x * EPB;
    int nval = N_EDGES - e0;
    if (nval > EPB) nval = EPB;
    int i64 = is_i64(fl);

    h[t] = 0;
    __syncthreads();
    for (int k = t; k < nval; k += 256) {
        int d = clampid(rd_dst(edge, i64, e0 + k));
        atomicAdd(&h[d / BSZ], 1);
    }
    __syncthreads();
    int c = h[t];
    excl[t] = c;
    __syncthreads();
    for (int off = 1; off < 256; off <<= 1) {
        int v = (t >= off) ? excl[t - off] : 0;
        __syncthreads();
        excl[t] += v;
        __syncthreads();
    }
    int myexcl = excl[t] - c;
    __syncthreads();
    excl[t] = myexcl;
    gbase[t] = (c > 0) ? atomicAdd(&bcur[t], c) : 0;
    lcur[t] = myexcl;
    __syncthreads();
    for (int k = t; k < nval; k += 256) {
        int s = clampid(rd_src(edge, i64, e0 + k));
        int d = clampid(rd_dst(edge, i64, e0 + k));
        int b = d / BSZ;
        int lp = atomicAdd(&lcur[b], 1);
        st[lp] = make_uint2((unsigned)s, (unsigned)d);
        binof[lp] = (unsigned char)b;
    }
    __syncthreads();
    for (int k = t; k < nval; k += 256) {
        int b = binof[k];
        pairs[gbase[b] + (k - excl[b])] = st[k];
    }
}

// ---- fused: per-(row,slice) hist -> scan -> rowptr2/dis emit -> place ----
// One block per dst bucket. csr within each row becomes src-slice-grouped.
__global__ void __launch_bounds__(1024) k_build(const uint2* __restrict__ pairs,
                                                const int* __restrict__ bbase,
                                                int* __restrict__ rp2,
                                                float* __restrict__ dis,
                                                int* __restrict__ csr) {
    __shared__ int hh[R8];      // (row,slice) counts -> within-row excl -> cursors
    __shared__ int rt[512];     // row-total scan
    int b = blockIdx.x;
    int t = threadIdx.x;
    int base = b * BSZ;
    for (int i = t; i < R8; i += 1024) hh[i] = 0;
    __syncthreads();
    int beg = bbase[b], end = bbase[b + 1];
    // pass 1: histogram by (row, src-slice)
    for (int i = beg + t; i < end; i += 1024) {
        uint2 p = pairs[i];
        int r = (int)p.y - base;
        int s = (int)p.x / SLW;
        atomicAdd(&hh[r * NSL + s], 1);
    }
    __syncthreads();
    // within-row exclusive scan over 8 slices; rtot = row degree
    int rtot = 0;
    if (t < BSZ) {
        int o = 0;
        for (int k = 0; k < NSL; k++) {
            int cc = hh[t * NSL + k];
            hh[t * NSL + k] = o;
            o += cc;
        }
        rtot = o;
    }
    if (t < 512) rt[t] = (t < BSZ) ? rtot : 0;
    __syncthreads();
    // block scan over 391 row totals (padded 512)
    for (int off = 1; off < 512; off <<= 1) {
        int v = 0;
        if (t < 512 && t >= off) v = rt[t - off];
        __syncthreads();
        if (t < 512 && t >= off) rt[t] += v;
        __syncthreads();
    }
    if (t < BSZ) {
        int gb = beg + (rt[t] - rtot);   // global row start
        int n = base + t;
        if (n < N_NODES) {
            dis[n] = (rtot > 0) ? rsqrtf((float)rtot) : 0.0f;
            for (int k = 0; k < NSL; k++) rp2[n * NSL + k] = gb + hh[t * NSL + k];
            if (n == N_NODES - 1) rp2[N_NODES * NSL] = N_EDGES;  // sentinel
        }
        for (int k = 0; k < NSL; k++) hh[t * NSL + k] += gb;     // -> global cursors
    }
    __syncthreads();
    // pass 2: place (slice-grouped within each row)
    for (int i = beg + t; i < end; i += 1024) {
        uint2 p = pairs[i];
        int r = (int)p.y - base;
        int s = (int)p.x / SLW;
        int pos = atomicAdd(&hh[r * NSL + s], 1);
        csr[pos] = (int)p.x;
    }
}

// out (fp32, = d_out) = emb; Y0 = bf16(dis ⊙ emb)
__global__ void k_init(const void* __restrict__ emb, const int* __restrict__ fl,
                       const float* __restrict__ dis,
                       float* __restrict__ out, bf16* __restrict__ Y) {
    int i = blockIdx.x * blockDim.x + threadIdx.x;
    if (i < ND) {
        float v = rd_emb(emb, fl, i);
        out[i] = v;
        Y[i] = __float2bfloat16(dis[i >> 6] * v);
    }
}

#define GATHER4(SRC)                                                     \
    {                                                                    \
        uint2 v = *(const uint2*)(Yu + (SRC) * 32 + l16 * 2);            \
        a0 += __uint_as_float(v.x << 16);                                \
        a1 += __uint_as_float(v.x & 0xffff0000u);                        \
        a2 += __uint_as_float(v.y << 16);                                \
        a3 += __uint_as_float(v.y & 0xffff0000u);                        \
    }

// persistent slice-major SpMM: all waves sweep src-slices 0..7 in order, so the
// instantaneous gather working set is ~2 slices (3.2MB) <= 4MB per-XCD L2.
// Per-wave LDS accumulators for SROWS rows; 16 lanes/edge, 4 edge-quarters.
__global__ void __launch_bounds__(256, 4) k_spmm(
        const int* __restrict__ rp2, const int* __restrict__ csr,
        const float* __restrict__ dis, const bf16* __restrict__ Yin,
        float* __restrict__ out, bf16* __restrict__ Yout, int last) {
    __shared__ float accs[4][SROWS][64];
    int wave = threadIdx.x >> 6;
    int lane = threadIdx.x & 63;
    int q    = lane >> 4;
    int l16  = lane & 15;
    int wg = blockIdx.x * 4 + wave;
    int r0 = wg * SROWS;
    for (int i = threadIdx.x; i < 4 * SROWS * 64; i += 256)
        ((float*)accs)[i] = 0.0f;
    __syncthreads();
    const unsigned* Yu = (const unsigned*)Yin;
    for (int s = 0; s < NSL; s++) {
        for (int ri = 0; ri < SROWS; ri++) {
            int n = r0 + ri;
            if (n >= N_NODES) break;
            int beg = rp2[n * NSL + s];
            int end = rp2[n * NSL + s + 1];   // s=7 -> next row's start (or sentinel)
            if (beg >= end) continue;
            float a0 = 0.f, a1 = 0.f, a2 = 0.f, a3 = 0.f;
            int j = beg;
            for (; j + 8 <= end; j += 8) {
                int s0 = csr[j + q];
                int s1 = csr[j + 4 + q];
                GATHER4(s0);
                GATHER4(s1);
            }
            if (j + q < end)     { int sv = csr[j + q];     GATHER4(sv); }
            if (j + 4 + q < end) { int sv = csr[j + 4 + q]; GATHER4(sv); }
            a0 += __shfl_xor(a0, 16); a0 += __shfl_xor(a0, 32);
            a1 += __shfl_xor(a1, 16); a1 += __shfl_xor(a1, 32);
            a2 += __shfl_xor(a2, 16); a2 += __shfl_xor(a2, 32);
            a3 += __shfl_xor(a3, 16); a3 += __shfl_xor(a3, 32);
            if (lane < 16) {
                float4* ap = (float4*)&accs[wave][ri][l16 * 4];
                float4 c = *ap;
                c.x += a0; c.y += a1; c.z += a2; c.w += a3;
                *ap = c;
            }
        }
    }
    // epilogue (nontemporal via native ext_vector types)
    for (int ri = 0; ri < SROWS; ri++) {
        int n = r0 + ri;
        if (n >= N_NODES) break;
        if (lane < 16) {
            float4 c = *(float4*)&accs[wave][ri][l16 * 4];
            float dn = dis[n];
            float x0 = dn * c.x, x1 = dn * c.y, x2 = dn * c.z, x3 = dn * c.w;
            int i4 = n * 16 + l16;
            f32x4 o = __builtin_nontemporal_load((const f32x4*)out + i4);
            if (last) {
                o.x = (o.x + x0) * 0.25f;
                o.y = (o.y + x1) * 0.25f;
                o.z = (o.z + x2) * 0.25f;
                o.w = (o.w + x3) * 0.25f;
                __builtin_nontemporal_store(o, (f32x4*)out + i4);
            } else {
                o.x += x0; o.y += x1; o.z += x2; o.w += x3;
                __builtin_nontemporal_store(o, (f32x4*)out + i4);
                bf16 t0 = __float2bfloat16(dn * x0);
                bf16 t1 = __float2bfloat16(dn * x1);
                bf16 t2 = __float2bfloat16(dn * x2);
                bf16 t3 = __float2bfloat16(dn * x3);
                u16x4 yv;
                yv.x = *(unsigned short*)&t0;
                yv.y = *(unsigned short*)&t1;
                yv.z = *(unsigned short*)&t2;
                yv.w = *(unsigned short*)&t3;
                __builtin_nontemporal_store(yv, (u16x4*)(Yout + n * EMBED) + l16);
            }
        }
    }
}

__global__ void k_fill42(float* __restrict__ o) {
    int i = blockIdx.x * blockDim.x + threadIdx.x;
    if (i < ND) o[i] = 42.0f;   // signature: ws too small for CSR layout
}

extern "C" void kernel_launch(void* const* d_in, const int* in_sizes, int n_in,
                              void* d_out, int out_size, void* d_ws, size_t ws_size,
                              hipStream_t stream) {
    const void* emb = d_in[0];
    const int* edge = (const int*)d_in[1];
    float* out = (float*)d_out;

    const int B = 256;
    const int gND = (ND + B - 1) / B;           // 25000
    const int gP  = (N_EDGES + EPB - 1) / EPB;  // 782 partition blocks

    char* ws = (char*)d_ws;
    int* fl = (int*)ws;
    size_t off = 256;
    const size_t off_dis   = off;  off += (size_t)N_NODES * 4;            // 400000
    const size_t off_rp2   = off;  off += (size_t)(N_NODES * NSL + 8) * 4; // 3200032
    const size_t off_bcnt  = off;  off += 1024;
    const size_t off_bbase = off;  off += 1056;
    const size_t off_bcur  = off;  off += 1024;
    const size_t off_csr   = off;  off += (size_t)N_EDGES * 4;
    const size_t off_Y0    = off;  off += (size_t)ND * 2;
    const size_t off_Y1    = off;  off += (size_t)ND * 2;
    const size_t need = off;                    // ~42.0 MB

    if (ws_size < need) {
        k_fill42<<<gND, B, 0, stream>>>(out);
        return;
    }

    float* dis   = (float*)(ws + off_dis);
    int*   rp2   = (int*)(ws + off_rp2);
    int*   bcnt  = (int*)(ws + off_bcnt);
    int*   bbase = (int*)(ws + off_bbase);
    int*   bcur  = (int*)(ws + off_bcur);
    int*   csr   = (int*)(ws + off_csr);
    uint2* pairs = (uint2*)(ws + off_Y0);       // 25.6MB, reuses Y0+Y1 (dead until k_init)
    bf16*  Y0    = (bf16*)(ws + off_Y0);
    bf16*  Y1    = (bf16*)(ws + off_Y1);

    k_flags0<<<1, 256, 0, stream>>>(fl, bcnt);
    k_scan_edge<<<1024, B, 0, stream>>>(edge, fl);
    k_scan_emb<<<1024, B, 0, stream>>>((const unsigned short*)emb, fl);

    // bucketed, slice-grouped CSR build
    k_bcnt<<<1024, B, 0, stream>>>(edge, fl, bcnt);
    k_bscan<<<1, 256, 0, stream>>>(bcnt, bbase, bcur);
    k_part<<<gP, B, 0, stream>>>(edge, fl, bcur, pairs);
    k_build<<<PNB, 1024, 0, stream>>>(pairs, bbase, rp2, dis, csr);

    k_init<<<gND, B, 0, stream>>>(emb, fl, dis, out, Y0);

    k_spmm<<<SGRID, B, 0, stream>>>(rp2, csr, dis, Y0, out, Y1, 0);
    k_spmm<<<SGRID, B, 0, stream>>>(rp2, csr, dis, Y1, out, Y0, 0);
    k_spmm<<<SGRID, B, 0, stream>>>(rp2, csr, dis, Y0, out, Y1, 1);
}

// Round 6
// 850.569 us; speedup vs baseline: 1.3501x; 1.3501x over previous
//
#include <hip/hip_runtime.h>
#include <hip/hip_bf16.h>

typedef __hip_bfloat16 bf16;
typedef float          f32x4 __attribute__((ext_vector_type(4)));
typedef unsigned short u16x4 __attribute__((ext_vector_type(4)));

#define N_NODES  100000
#define EMBED    64
#define N_EDGES  3200000
#define ND       6400000
#define N_LAYERS 3

// bucketed CSR build
#define PNB  256            // number of dst buckets
#define BSZ  391            // nodes per bucket (256*391 = 100096 >= N_NODES)
#define EPB  4096           // edges per partition block
#define NSL  8              // src slices inside a row (harmless leftover grouping)
#define SLW  12512          // slice width
#define R8   (BSZ * NSL)    // 3128 per-bucket (row,slice) bins

// column-split spmm: 4 splits of 16 cols; per-split Y region = 3.2MB <= 4MB L2
#define NSPL 4

// flags: [0] edge_nz  [1] emb_outl

__global__ void k_flags0(int* f, int* bcnt) {
    int t = threadIdx.x;
    if (t < 16) f[t] = 0;
    bcnt[t] = 0;
}

// int64 [2,E] viewed as i32 words: odd words (high halves) all zero.
__global__ void k_scan_edge(const int* __restrict__ edge, int* __restrict__ fl) {
    long long step = (long long)gridDim.x * blockDim.x;
    int found = 0;
    for (long long j = (long long)blockIdx.x * blockDim.x + threadIdx.x;
         j < N_EDGES; j += step)
        if (edge[2 * j + 1] != 0) found = 1;
    if (found) atomicOr(&fl[0], 1);
}

// bf16 census (safety; expected fp32)
__global__ void k_scan_emb(const unsigned short* __restrict__ u, int* __restrict__ fl) {
    long long step = (long long)gridDim.x * blockDim.x;
    int local = 0;
    for (long long j = (long long)blockIdx.x * blockDim.x + threadIdx.x;
         j < ND; j += step) {
        unsigned b = (u[j] >> 8) & 0x7f;
        if (b < 0x2e || b > 0x41) local++;
    }
    if (local) atomicAdd(&fl[1], local);
}

__device__ __forceinline__ int is_i64(const int* fl) { return fl[0] == 0; }
__device__ __forceinline__ int rd_src(const int* e, int i64, int k) {
    return i64 ? e[2 * k] : e[k];
}
__device__ __forceinline__ int rd_dst(const int* e, int i64, int k) {
    return i64 ? e[2 * (N_EDGES + k)] : e[N_EDGES + k];
}
__device__ __forceinline__ int clampid(int v) {
    return (v < 0) ? 0 : ((v >= N_NODES) ? (N_NODES - 1) : v);
}
__device__ __forceinline__ float rd_emb(const void* emb, const int* fl, int i) {
    if (fl[1] < (ND / 16)) return __bfloat162float(((const bf16*)emb)[i]);
    return ((const float*)emb)[i];
}

// ---- coarse bucket counts (LDS hist, 256 bins) ----
__global__ void __launch_bounds__(256) k_bcnt(const int* __restrict__ edge,
                                              const int* __restrict__ fl,
                                              int* __restrict__ bcnt) {
    __shared__ int h[PNB];
    int t = threadIdx.x;
    h[t] = 0;
    __syncthreads();
    int i64 = is_i64(fl);
    int step = gridDim.x * 256;
    for (int e = blockIdx.x * 256 + t; e < N_EDGES; e += step) {
        int d = clampid(rd_dst(edge, i64, e));
        atomicAdd(&h[d / BSZ], 1);
    }
    __syncthreads();
    if (h[t]) atomicAdd(&bcnt[t], h[t]);
}

// ---- parallel exclusive scan of bucket counts (1 block) ----
__global__ void __launch_bounds__(256) k_bscan(const int* __restrict__ bcnt,
                                               int* __restrict__ bbase,
                                               int* __restrict__ bcur) {
    __shared__ int sb[PNB];
    int t = threadIdx.x;
    int c = bcnt[t];
    sb[t] = c;
    __syncthreads();
    for (int off = 1; off < PNB; off <<= 1) {
        int v = (t >= off) ? sb[t - off] : 0;
        __syncthreads();
        sb[t] += v;
        __syncthreads();
    }
    int ex = sb[t] - c;
    bbase[t] = ex;
    bcur[t] = ex;
    if (t == PNB - 1) bbase[PNB] = sb[t];
}

// ---- partition edges into dst-buckets, LDS counting sort per 4096-edge block ----
__global__ void __launch_bounds__(256) k_part(const int* __restrict__ edge,
                                              const int* __restrict__ fl,
                                              int* __restrict__ bcur,
                                              uint2* __restrict__ pairs) {
    __shared__ int h[PNB];
    __shared__ int excl[PNB];
    __shared__ int gbase[PNB];
    __shared__ int lcur[PNB];
    __shared__ uint2 st[EPB];
    __shared__ unsigned char binof[EPB];
    int t = threadIdx.x;
    int e0 = blockIdx.x * EPB;
    int nval = N_EDGES - e0;
    if (nval > EPB) nval = EPB;
    int i64 = is_i64(fl);

    h[t] = 0;
    __syncthreads();
    for (int k = t; k < nval; k += 256) {
        int d = clampid(rd_dst(edge, i64, e0 + k));
        atomicAdd(&h[d / BSZ], 1);
    }
    __syncthreads();
    int c = h[t];
    excl[t] = c;
    __syncthreads();
    for (int off = 1; off < 256; off <<= 1) {
        int v = (t >= off) ? excl[t - off] : 0;
        __syncthreads();
        excl[t] += v;
        __syncthreads();
    }
    int myexcl = excl[t] - c;
    __syncthreads();
    excl[t] = myexcl;
    gbase[t] = (c > 0) ? atomicAdd(&bcur[t], c) : 0;
    lcur[t] = myexcl;
    __syncthreads();
    for (int k = t; k < nval; k += 256) {
        int s = clampid(rd_src(edge, i64, e0 + k));
        int d = clampid(rd_dst(edge, i64, e0 + k));
        int b = d / BSZ;
        int lp = atomicAdd(&lcur[b], 1);
        st[lp] = make_uint2((unsigned)s, (unsigned)d);
        binof[lp] = (unsigned char)b;
    }
    __syncthreads();
    for (int k = t; k < nval; k += 256) {
        int b = binof[k];
        pairs[gbase[b] + (k - excl[b])] = st[k];
    }
}

// ---- fused: per-(row,slice) hist -> scan -> rowptr2/dis emit -> place ----
__global__ void __launch_bounds__(1024) k_build(const uint2* __restrict__ pairs,
                                                const int* __restrict__ bbase,
                                                int* __restrict__ rp2,
                                                float* __restrict__ dis,
                                                int* __restrict__ csr) {
    __shared__ int hh[R8];      // (row,slice) counts -> within-row excl -> cursors
    __shared__ int rt[512];     // row-total scan
    int b = blockIdx.x;
    int t = threadIdx.x;
    int base = b * BSZ;
    for (int i = t; i < R8; i += 1024) hh[i] = 0;
    __syncthreads();
    int beg = bbase[b], end = bbase[b + 1];
    for (int i = beg + t; i < end; i += 1024) {
        uint2 p = pairs[i];
        int r = (int)p.y - base;
        int s = (int)p.x / SLW;
        atomicAdd(&hh[r * NSL + s], 1);
    }
    __syncthreads();
    int rtot = 0;
    if (t < BSZ) {
        int o = 0;
        for (int k = 0; k < NSL; k++) {
            int cc = hh[t * NSL + k];
            hh[t * NSL + k] = o;
            o += cc;
        }
        rtot = o;
    }
    if (t < 512) rt[t] = (t < BSZ) ? rtot : 0;
    __syncthreads();
    for (int off = 1; off < 512; off <<= 1) {
        int v = 0;
        if (t < 512 && t >= off) v = rt[t - off];
        __syncthreads();
        if (t < 512 && t >= off) rt[t] += v;
        __syncthreads();
    }
    if (t < BSZ) {
        int gb = beg + (rt[t] - rtot);   // global row start
        int n = base + t;
        if (n < N_NODES) {
            dis[n] = (rtot > 0) ? rsqrtf((float)rtot) : 0.0f;
            for (int k = 0; k < NSL; k++) rp2[n * NSL + k] = gb + hh[t * NSL + k];
            if (n == N_NODES - 1) rp2[N_NODES * NSL] = N_EDGES;  // sentinel
        }
        for (int k = 0; k < NSL; k++) hh[t * NSL + k] += gb;
    }
    __syncthreads();
    for (int i = beg + t; i < end; i += 1024) {
        uint2 p = pairs[i];
        int r = (int)p.y - base;
        int s = (int)p.x / SLW;
        int pos = atomicAdd(&hh[r * NSL + s], 1);
        csr[pos] = (int)p.x;
    }
}

// out (fp32, = d_out) = emb; Y0 = bf16(dis ⊙ emb) in SPLIT-MAJOR layout:
// Y[split][node][16 cols], split = col>>4 — each split region is 3.2MB.
__global__ void k_init(const void* __restrict__ emb, const int* __restrict__ fl,
                       const float* __restrict__ dis,
                       float* __restrict__ out, bf16* __restrict__ Y) {
    int i = blockIdx.x * blockDim.x + threadIdx.x;
    if (i < ND) {
        float v = rd_emb(emb, fl, i);
        out[i] = v;
        int n = i >> 6, cc = i & 63;
        Y[(size_t)(cc >> 4) * (N_NODES * 16) + n * 16 + (cc & 15)] =
            __float2bfloat16(dis[n] * v);
    }
}

// wave-per-row column-split SpMM. One dispatch per (layer, split s):
// gathers touch only Y[s] (3.2MB, L2-resident). Lane: e=lane>>2 (16 edges
// in flight per load), c=lane&3 (4 cols each, uint2=4 bf16).
__global__ void __launch_bounds__(256) k_spmm(
        const int* __restrict__ rp2, const int* __restrict__ csr,
        const float* __restrict__ dis, const bf16* __restrict__ Yin,
        float* __restrict__ out, bf16* __restrict__ Yout, int s, int last) {
    int wave = threadIdx.x >> 6;
    int lane = threadIdx.x & 63;
    int e = lane >> 2;
    int c = lane & 3;
    int n = blockIdx.x * 4 + wave;
    if (n >= N_NODES) return;
    int beg = rp2[n * NSL];
    int end = rp2[(n + 1) * NSL];          // sentinel covers n = N_NODES-1
    const unsigned* Ys = (const unsigned*)Yin + (size_t)s * (N_NODES * 8);
    float a0 = 0.f, a1 = 0.f, a2 = 0.f, a3 = 0.f;
    int j = beg;
    for (; j + 16 <= end; j += 16) {
        int src = csr[j + e];
        uint2 v = *(const uint2*)(Ys + src * 8 + c * 2);
        a0 += __uint_as_float(v.x << 16);
        a1 += __uint_as_float(v.x & 0xffff0000u);
        a2 += __uint_as_float(v.y << 16);
        a3 += __uint_as_float(v.y & 0xffff0000u);
    }
    if (j + e < end) {
        int src = csr[j + e];
        uint2 v = *(const uint2*)(Ys + src * 8 + c * 2);
        a0 += __uint_as_float(v.x << 16);
        a1 += __uint_as_float(v.x & 0xffff0000u);
        a2 += __uint_as_float(v.y << 16);
        a3 += __uint_as_float(v.y & 0xffff0000u);
    }
    // reduce across the 16 edge groups (stride 4 lanes)
    a0 += __shfl_xor(a0, 4); a0 += __shfl_xor(a0, 8);
    a0 += __shfl_xor(a0, 16); a0 += __shfl_xor(a0, 32);
    a1 += __shfl_xor(a1, 4); a1 += __shfl_xor(a1, 8);
    a1 += __shfl_xor(a1, 16); a1 += __shfl_xor(a1, 32);
    a2 += __shfl_xor(a2, 4); a2 += __shfl_xor(a2, 8);
    a2 += __shfl_xor(a2, 16); a2 += __shfl_xor(a2, 32);
    a3 += __shfl_xor(a3, 4); a3 += __shfl_xor(a3, 8);
    a3 += __shfl_xor(a3, 16); a3 += __shfl_xor(a3, 32);
    if (lane < 4) {                        // lane == c
        float dn = dis[n];
        float x0 = dn * a0, x1 = dn * a1, x2 = dn * a2, x3 = dn * a3;
        int i4 = n * 16 + s * 4 + lane;    // float4 idx: cols s*16 + lane*4 ..
        f32x4 o = __builtin_nontemporal_load((const f32x4*)out + i4);
        if (last) {
            o.x = (o.x + x0) * 0.25f;
            o.y = (o.y + x1) * 0.25f;
            o.z = (o.z + x2) * 0.25f;
            o.w = (o.w + x3) * 0.25f;
            __builtin_nontemporal_store(o, (f32x4*)out + i4);
        } else {
            o.x += x0; o.y += x1; o.z += x2; o.w += x3;
            __builtin_nontemporal_store(o, (f32x4*)out + i4);
            bf16 t0 = __float2bfloat16(dn * x0);
            bf16 t1 = __float2bfloat16(dn * x1);
            bf16 t2 = __float2bfloat16(dn * x2);
            bf16 t3 = __float2bfloat16(dn * x3);
            u16x4 yv;
            yv.x = *(unsigned short*)&t0;
            yv.y = *(unsigned short*)&t1;
            yv.z = *(unsigned short*)&t2;
            yv.w = *(unsigned short*)&t3;
            // split-major Yout: region s, node n, col-group c
            __builtin_nontemporal_store(
                yv, (u16x4*)Yout + (size_t)s * (N_NODES * 4) + n * 4 + lane);
        }
    }
}

__global__ void k_fill42(float* __restrict__ o) {
    int i = blockIdx.x * blockDim.x + threadIdx.x;
    if (i < ND) o[i] = 42.0f;   // signature: ws too small for CSR layout
}

extern "C" void kernel_launch(void* const* d_in, const int* in_sizes, int n_in,
                              void* d_out, int out_size, void* d_ws, size_t ws_size,
                              hipStream_t stream) {
    const void* emb = d_in[0];
    const int* edge = (const int*)d_in[1];
    float* out = (float*)d_out;

    const int B = 256;
    const int gND = (ND + B - 1) / B;           // 25000
    const int gP  = (N_EDGES + EPB - 1) / EPB;  // 782 partition blocks
    const int gW  = (N_NODES + 3) / 4;          // 25000 wave-per-row blocks

    char* ws = (char*)d_ws;
    int* fl = (int*)ws;
    size_t off = 256;
    const size_t off_dis   = off;  off += (size_t)N_NODES * 4;
    const size_t off_rp2   = off;  off += (size_t)(N_NODES * NSL + 8) * 4;
    const size_t off_bcnt  = off;  off += 1024;
    const size_t off_bbase = off;  off += 1056;
    const size_t off_bcur  = off;  off += 1024;
    const size_t off_csr   = off;  off += (size_t)N_EDGES * 4;
    const size_t off_Y0    = off;  off += (size_t)ND * 2;
    const size_t off_Y1    = off;  off += (size_t)ND * 2;
    const size_t need = off;                    // ~42.0 MB

    if (ws_size < need) {
        k_fill42<<<gND, B, 0, stream>>>(out);
        return;
    }

    float* dis   = (float*)(ws + off_dis);
    int*   rp2   = (int*)(ws + off_rp2);
    int*   bcnt  = (int*)(ws + off_bcnt);
    int*   bbase = (int*)(ws + off_bbase);
    int*   bcur  = (int*)(ws + off_bcur);
    int*   csr   = (int*)(ws + off_csr);
    uint2* pairs = (uint2*)(ws + off_Y0);       // 25.6MB, reuses Y0+Y1 (dead until k_init)
    bf16*  Y0    = (bf16*)(ws + off_Y0);
    bf16*  Y1    = (bf16*)(ws + off_Y1);

    k_flags0<<<1, 256, 0, stream>>>(fl, bcnt);
    k_scan_edge<<<1024, B, 0, stream>>>(edge, fl);
    k_scan_emb<<<1024, B, 0, stream>>>((const unsigned short*)emb, fl);

    // bucketed CSR build
    k_bcnt<<<1024, B, 0, stream>>>(edge, fl, bcnt);
    k_bscan<<<1, 256, 0, stream>>>(bcnt, bbase, bcur);
    k_part<<<gP, B, 0, stream>>>(edge, fl, bcur, pairs);
    k_build<<<PNB, 1024, 0, stream>>>(pairs, bbase, rp2, dis, csr);

    k_init<<<gND, B, 0, stream>>>(emb, fl, dis, out, Y0);

    for (int s = 0; s < NSPL; s++)
        k_spmm<<<gW, B, 0, stream>>>(rp2, csr, dis, Y0, out, Y1, s, 0);
    for (int s = 0; s < NSPL; s++)
        k_spmm<<<gW, B, 0, stream>>>(rp2, csr, dis, Y1, out, Y0, s, 0);
    for (int s = 0; s < NSPL; s++)
        k_spmm<<<gW, B, 0, stream>>>(rp2, csr, dis, Y0, out, Y1, s, 1);
}

// Round 7
// 735.824 us; speedup vs baseline: 1.5607x; 1.1559x over previous
//
#include <hip/hip_runtime.h>
#include <hip/hip_bf16.h>

typedef __hip_bfloat16 bf16;
typedef float          f32x4 __attribute__((ext_vector_type(4)));
typedef unsigned short u16x4 __attribute__((ext_vector_type(4)));

#define N_NODES  100000
#define EMBED    64
#define N_EDGES  3200000
#define ND       6400000
#define N_LAYERS 3

// bucketed CSR build
#define PNB  256            // number of dst buckets
#define BSZ  391            // nodes per bucket (256*391 = 100096 >= N_NODES)
#define EPB  4096           // edges per partition block
#define NSL  8              // src slices inside a row (grouping within rows)
#define SLW  12512          // slice width
#define R8   (BSZ * NSL)    // 3128 per-bucket (row,slice) bins

// column-split spmm: 4 splits of 16 cols; per-split Y region = 3.2MB <= 4MB L2
#define NSPL 4

// flags: [0] edge_nz  [1] emb_outl

__global__ void k_flags0(int* f, int* bcnt) {
    int t = threadIdx.x;
    if (t < 16) f[t] = 0;
    bcnt[t] = 0;
}

// fused vectorized input census: edge odd-word check + emb u16 exponent census.
// Reads the SAME byte ranges as the old scalar k_scan_edge / k_scan_emb.
__global__ void __launch_bounds__(256) k_scan(const uint4* __restrict__ edge4,
                                              const uint4* __restrict__ emb4,
                                              int* __restrict__ fl) {
    int gid = blockIdx.x * 256 + threadIdx.x;
    int step = gridDim.x * 256;
    // edge: words [0, 2*N_EDGES) as uint4; odd words are .y/.w
    int found = 0;
    const int NV_E = (2 * N_EDGES) / 4;        // 1,600,000 vecs
    for (int i = gid; i < NV_E; i += step) {
        uint4 v = edge4[i];
        if ((v.y | v.w) != 0) found = 1;
    }
    if (found) atomicOr(&fl[0], 1);
    // emb: first ND u16 as uint4 (8 u16 each)
    int local = 0;
    const int NV_M = ND / 8;                   // 800,000 vecs
    for (int i = gid; i < NV_M; i += step) {
        uint4 v = emb4[i];
        unsigned w0 = v.x, w1 = v.y, w2 = v.z, w3 = v.w;
        unsigned b;
        b = (w0 >> 8)  & 0x7f; if (b < 0x2e || b > 0x41) local++;
        b = (w0 >> 24) & 0x7f; if (b < 0x2e || b > 0x41) local++;
        b = (w1 >> 8)  & 0x7f; if (b < 0x2e || b > 0x41) local++;
        b = (w1 >> 24) & 0x7f; if (b < 0x2e || b > 0x41) local++;
        b = (w2 >> 8)  & 0x7f; if (b < 0x2e || b > 0x41) local++;
        b = (w2 >> 24) & 0x7f; if (b < 0x2e || b > 0x41) local++;
        b = (w3 >> 8)  & 0x7f; if (b < 0x2e || b > 0x41) local++;
        b = (w3 >> 24) & 0x7f; if (b < 0x2e || b > 0x41) local++;
    }
    if (local) atomicAdd(&fl[1], local);
}

__device__ __forceinline__ int is_i64(const int* fl) { return fl[0] == 0; }
__device__ __forceinline__ int rd_src(const int* e, int i64, int k) {
    return i64 ? e[2 * k] : e[k];
}
__device__ __forceinline__ int rd_dst(const int* e, int i64, int k) {
    return i64 ? e[2 * (N_EDGES + k)] : e[N_EDGES + k];
}
__device__ __forceinline__ int clampid(int v) {
    return (v < 0) ? 0 : ((v >= N_NODES) ? (N_NODES - 1) : v);
}
__device__ __forceinline__ float rd_emb(const void* emb, const int* fl, int i) {
    if (fl[1] < (ND / 16)) return __bfloat162float(((const bf16*)emb)[i]);
    return ((const float*)emb)[i];
}

// ---- coarse bucket counts (LDS hist, 256 bins), uint4 dst-half loads ----
__global__ void __launch_bounds__(256) k_bcnt(const int* __restrict__ edge,
                                              const int* __restrict__ fl,
                                              int* __restrict__ bcnt) {
    __shared__ int h[PNB];
    int t = threadIdx.x;
    h[t] = 0;
    __syncthreads();
    const uint4* e4 = (const uint4*)edge;
    int gid = blockIdx.x * 256 + t;
    int step = gridDim.x * 256;
    if (is_i64(fl)) {
        const int base = N_EDGES / 2;          // dst half: word 2*N_EDGES -> vec idx
        const int nv   = N_EDGES / 2;          // 1.6M vecs (2 edges each)
        for (int i = gid; i < nv; i += step) {
            uint4 v = e4[base + i];
            atomicAdd(&h[clampid((int)v.x) / BSZ], 1);
            atomicAdd(&h[clampid((int)v.z) / BSZ], 1);
        }
    } else {
        const int base = N_EDGES / 4;          // dst half at word N_EDGES
        const int nv   = N_EDGES / 4;          // 800K vecs (4 edges each)
        for (int i = gid; i < nv; i += step) {
            uint4 v = e4[base + i];
            atomicAdd(&h[clampid((int)v.x) / BSZ], 1);
            atomicAdd(&h[clampid((int)v.y) / BSZ], 1);
            atomicAdd(&h[clampid((int)v.z) / BSZ], 1);
            atomicAdd(&h[clampid((int)v.w) / BSZ], 1);
        }
    }
    __syncthreads();
    if (h[t]) atomicAdd(&bcnt[t], h[t]);
}

// ---- parallel exclusive scan of bucket counts (1 block) ----
__global__ void __launch_bounds__(256) k_bscan(const int* __restrict__ bcnt,
                                               int* __restrict__ bbase,
                                               int* __restrict__ bcur) {
    __shared__ int sb[PNB];
    int t = threadIdx.x;
    int c = bcnt[t];
    sb[t] = c;
    __syncthreads();
    for (int off = 1; off < PNB; off <<= 1) {
        int v = (t >= off) ? sb[t - off] : 0;
        __syncthreads();
        sb[t] += v;
        __syncthreads();
    }
    int ex = sb[t] - c;
    bbase[t] = ex;
    bcur[t] = ex;
    if (t == PNB - 1) bbase[PNB] = sb[t];
}

// ---- partition edges into dst-buckets, LDS counting sort per 4096-edge block ----
__global__ void __launch_bounds__(256) k_part(const int* __restrict__ edge,
                                              const int* __restrict__ fl,
                                              int* __restrict__ bcur,
                                              uint2* __restrict__ pairs) {
    __shared__ int h[PNB];
    __shared__ int excl[PNB];
    __shared__ int gbase[PNB];
    __shared__ int lcur[PNB];
    __shared__ uint2 st[EPB];
    __shared__ unsigned char binof[EPB];
    int t = threadIdx.x;
    int e0 = blockIdx.x * EPB;
    int nval = N_EDGES - e0;
    if (nval > EPB) nval = EPB;
    int i64 = is_i64(fl);

    h[t] = 0;
    __syncthreads();
    for (int k = t; k < nval; k += 256) {
        int d = clampid(rd_dst(edge, i64, e0 + k));
        atomicAdd(&h[d / BSZ], 1);
    }
    __syncthreads();
    int c = h[t];
    excl[t] = c;
    __syncthreads();
    for (int off = 1; off < 256; off <<= 1) {
        int v = (t >= off) ? excl[t - off] : 0;
        __syncthreads();
        excl[t] += v;
        __syncthreads();
    }
    int myexcl = excl[t] - c;
    __syncthreads();
    excl[t] = myexcl;
    gbase[t] = (c > 0) ? atomicAdd(&bcur[t], c) : 0;
    lcur[t] = myexcl;
    __syncthreads();
    for (int k = t; k < nval; k += 256) {
        int s = clampid(rd_src(edge, i64, e0 + k));
        int d = clampid(rd_dst(edge, i64, e0 + k));
        int b = d / BSZ;
        int lp = atomicAdd(&lcur[b], 1);
        st[lp] = make_uint2((unsigned)s, (unsigned)d);
        binof[lp] = (unsigned char)b;
    }
    __syncthreads();
    for (int k = t; k < nval; k += 256) {
        int b = binof[k];
        pairs[gbase[b] + (k - excl[b])] = st[k];
    }
}

// ---- fused: per-(row,slice) hist -> scan -> rowptr2/dis emit -> place ----
__global__ void __launch_bounds__(1024) k_build(const uint2* __restrict__ pairs,
                                                const int* __restrict__ bbase,
                                                int* __restrict__ rp2,
                                                float* __restrict__ dis,
                                                int* __restrict__ csr) {
    __shared__ int hh[R8];      // (row,slice) counts -> within-row excl -> cursors
    __shared__ int rt[512];     // row-total scan
    int b = blockIdx.x;
    int t = threadIdx.x;
    int base = b * BSZ;
    for (int i = t; i < R8; i += 1024) hh[i] = 0;
    __syncthreads();
    int beg = bbase[b], end = bbase[b + 1];
    for (int i = beg + t; i < end; i += 1024) {
        uint2 p = pairs[i];
        int r = (int)p.y - base;
        int s = (int)p.x / SLW;
        atomicAdd(&hh[r * NSL + s], 1);
    }
    __syncthreads();
    int rtot = 0;
    if (t < BSZ) {
        int o = 0;
        for (int k = 0; k < NSL; k++) {
            int cc = hh[t * NSL + k];
            hh[t * NSL + k] = o;
            o += cc;
        }
        rtot = o;
    }
    if (t < 512) rt[t] = (t < BSZ) ? rtot : 0;
    __syncthreads();
    for (int off = 1; off < 512; off <<= 1) {
        int v = 0;
        if (t < 512 && t >= off) v = rt[t - off];
        __syncthreads();
        if (t < 512 && t >= off) rt[t] += v;
        __syncthreads();
    }
    if (t < BSZ) {
        int gb = beg + (rt[t] - rtot);   // global row start
        int n = base + t;
        if (n < N_NODES) {
            dis[n] = (rtot > 0) ? rsqrtf((float)rtot) : 0.0f;
            for (int k = 0; k < NSL; k++) rp2[n * NSL + k] = gb + hh[t * NSL + k];
            if (n == N_NODES - 1) rp2[N_NODES * NSL] = N_EDGES;  // sentinel
        }
        for (int k = 0; k < NSL; k++) hh[t * NSL + k] += gb;
    }
    __syncthreads();
    for (int i = beg + t; i < end; i += 1024) {
        uint2 p = pairs[i];
        int r = (int)p.y - base;
        int s = (int)p.x / SLW;
        int pos = atomicAdd(&hh[r * NSL + s], 1);
        csr[pos] = (int)p.x;
    }
}

// out (fp32, = d_out) = emb; Y0 = bf16(dis ⊙ emb) in SPLIT-MAJOR layout:
// Y[split][node][16 cols], split = col>>4 — each split region is 3.2MB.
__global__ void k_init(const void* __restrict__ emb, const int* __restrict__ fl,
                       const float* __restrict__ dis,
                       float* __restrict__ out, bf16* __restrict__ Y) {
    int i = blockIdx.x * blockDim.x + threadIdx.x;
    if (i < ND) {
        float v = rd_emb(emb, fl, i);
        out[i] = v;
        int n = i >> 6, cc = i & 63;
        Y[(size_t)(cc >> 4) * (N_NODES * 16) + n * 16 + (cc & 15)] =
            __float2bfloat16(dis[n] * v);
    }
}

#define GATHER4(SRC)                                                     \
    {                                                                    \
        uint2 v = *(const uint2*)(Ys + (SRC) * 8 + c * 2);               \
        a0 += __uint_as_float(v.x << 16);                                \
        a1 += __uint_as_float(v.x & 0xffff0000u);                        \
        a2 += __uint_as_float(v.y << 16);                                \
        a3 += __uint_as_float(v.y & 0xffff0000u);                        \
    }

// column-split SpMM, 4 rows per wave: 16 lanes per row (4 edge slots x 4
// col-groups). Reduce = shfl_xor 4,8 only (8 shfls per 4 rows, was 16/row).
// One dispatch per (layer, split s): gathers touch only Y[s] (3.2MB, L2-fit).
__global__ void __launch_bounds__(256) k_spmm(
        const int* __restrict__ rp2, const int* __restrict__ csr,
        const float* __restrict__ dis, const bf16* __restrict__ Yin,
        float* __restrict__ out, bf16* __restrict__ Yout, int s, int last) {
    int wave = threadIdx.x >> 6;
    int lane = threadIdx.x & 63;
    int g = lane >> 4;          // row group within wave
    int l = lane & 15;
    int e = l >> 2;             // 4 edge slots
    int c = l & 3;              // col group (4 bf16 = 8B)
    int n = (blockIdx.x * 4 + wave) * 4 + g;
    if (n >= N_NODES) return;
    int beg = rp2[n * NSL];
    int end = rp2[(n + 1) * NSL];          // sentinel covers n = N_NODES-1
    const unsigned* Ys = (const unsigned*)Yin + (size_t)s * (N_NODES * 8);
    float a0 = 0.f, a1 = 0.f, a2 = 0.f, a3 = 0.f;
    int j = beg;
    for (; j + 8 <= end; j += 8) {
        int s0 = csr[j + e];
        int s1 = csr[j + 4 + e];
        GATHER4(s0);
        GATHER4(s1);
    }
    if (j + e < end)     { int sv = csr[j + e];     GATHER4(sv); }
    if (j + 4 + e < end) { int sv = csr[j + 4 + e]; GATHER4(sv); }
    // reduce across the 4 edge slots (stays inside each 16-lane row group)
    a0 += __shfl_xor(a0, 4); a0 += __shfl_xor(a0, 8);
    a1 += __shfl_xor(a1, 4); a1 += __shfl_xor(a1, 8);
    a2 += __shfl_xor(a2, 4); a2 += __shfl_xor(a2, 8);
    a3 += __shfl_xor(a3, 4); a3 += __shfl_xor(a3, 8);
    if (e == 0) {               // 4 lanes per row group, l == c
        float dn = dis[n];
        float x0 = dn * a0, x1 = dn * a1, x2 = dn * a2, x3 = dn * a3;
        int i4 = n * 16 + s * 4 + c;       // float4 idx: cols s*16 + c*4 ..
        f32x4 o = __builtin_nontemporal_load((const f32x4*)out + i4);
        if (last) {
            o.x = (o.x + x0) * 0.25f;
            o.y = (o.y + x1) * 0.25f;
            o.z = (o.z + x2) * 0.25f;
            o.w = (o.w + x3) * 0.25f;
            __builtin_nontemporal_store(o, (f32x4*)out + i4);
        } else {
            o.x += x0; o.y += x1; o.z += x2; o.w += x3;
            __builtin_nontemporal_store(o, (f32x4*)out + i4);
            bf16 t0 = __float2bfloat16(dn * x0);
            bf16 t1 = __float2bfloat16(dn * x1);
            bf16 t2 = __float2bfloat16(dn * x2);
            bf16 t3 = __float2bfloat16(dn * x3);
            u16x4 yv;
            yv.x = *(unsigned short*)&t0;
            yv.y = *(unsigned short*)&t1;
            yv.z = *(unsigned short*)&t2;
            yv.w = *(unsigned short*)&t3;
            // split-major Yout: region s, node n, col-group c
            __builtin_nontemporal_store(
                yv, (u16x4*)Yout + (size_t)s * (N_NODES * 4) + n * 4 + c);
        }
    }
}

__global__ void k_fill42(float* __restrict__ o) {
    int i = blockIdx.x * blockDim.x + threadIdx.x;
    if (i < ND) o[i] = 42.0f;   // signature: ws too small for CSR layout
}

extern "C" void kernel_launch(void* const* d_in, const int* in_sizes, int n_in,
                              void* d_out, int out_size, void* d_ws, size_t ws_size,
                              hipStream_t stream) {
    const void* emb = d_in[0];
    const int* edge = (const int*)d_in[1];
    float* out = (float*)d_out;

    const int B = 256;
    const int gND = (ND + B - 1) / B;           // 25000
    const int gP  = (N_EDGES + EPB - 1) / EPB;  // 782 partition blocks
    const int gW  = (N_NODES + 15) / 16;        // 6250 (4 rows/wave, 4 waves/blk)

    char* ws = (char*)d_ws;
    int* fl = (int*)ws;
    size_t off = 256;
    const size_t off_dis   = off;  off += (size_t)N_NODES * 4;
    const size_t off_rp2   = off;  off += (size_t)(N_NODES * NSL + 8) * 4;
    const size_t off_bcnt  = off;  off += 1024;
    const size_t off_bbase = off;  off += 1056;
    const size_t off_bcur  = off;  off += 1024;
    const size_t off_csr   = off;  off += (size_t)N_EDGES * 4;
    const size_t off_Y0    = off;  off += (size_t)ND * 2;
    const size_t off_Y1    = off;  off += (size_t)ND * 2;
    const size_t need = off;                    // ~42.0 MB

    if (ws_size < need) {
        k_fill42<<<gND, B, 0, stream>>>(out);
        return;
    }

    float* dis   = (float*)(ws + off_dis);
    int*   rp2   = (int*)(ws + off_rp2);
    int*   bcnt  = (int*)(ws + off_bcnt);
    int*   bbase = (int*)(ws + off_bbase);
    int*   bcur  = (int*)(ws + off_bcur);
    int*   csr   = (int*)(ws + off_csr);
    uint2* pairs = (uint2*)(ws + off_Y0);       // 25.6MB, reuses Y0+Y1 (dead until k_init)
    bf16*  Y0    = (bf16*)(ws + off_Y0);
    bf16*  Y1    = (bf16*)(ws + off_Y1);

    k_flags0<<<1, 256, 0, stream>>>(fl, bcnt);
    k_scan<<<2048, B, 0, stream>>>((const uint4*)edge, (const uint4*)emb, fl);

    // bucketed CSR build
    k_bcnt<<<1024, B, 0, stream>>>(edge, fl, bcnt);
    k_bscan<<<1, 256, 0, stream>>>(bcnt, bbase, bcur);
    k_part<<<gP, B, 0, stream>>>(edge, fl, bcur, pairs);
    k_build<<<PNB, 1024, 0, stream>>>(pairs, bbase, rp2, dis, csr);

    k_init<<<gND, B, 0, stream>>>(emb, fl, dis, out, Y0);

    for (int s = 0; s < NSPL; s++)
        k_spmm<<<gW, B, 0, stream>>>(rp2, csr, dis, Y0, out, Y1, s, 0);
    for (int s = 0; s < NSPL; s++)
        k_spmm<<<gW, B, 0, stream>>>(rp2, csr, dis, Y1, out, Y0, s, 0);
    for (int s = 0; s < NSPL; s++)
        k_spmm<<<gW, B, 0, stream>>>(rp2, csr, dis, Y0, out, Y1, s, 1);
}

// Round 8
// 504.282 us; speedup vs baseline: 2.2772x; 1.4592x over previous
//
#include <hip/hip_runtime.h>
#include <hip/hip_bf16.h>

typedef __hip_bfloat16 bf16;
typedef float          f32x4 __attribute__((ext_vector_type(4)));
typedef unsigned short u16x4 __attribute__((ext_vector_type(4)));

#define N_NODES  100000
#define EMBED    64
#define N_EDGES  3200000
#define ND       6400000
#define N_LAYERS 3

// bucketed CSR build
#define PNB  256            // number of dst buckets
#define BSZ  391            // nodes per bucket (256*391 = 100096 >= N_NODES)
#define EPB  4096           // edges per partition block
#define NSL  8              // src slices inside a row (grouping within rows)
#define SLW  12512          // slice width
#define R8   (BSZ * NSL)    // 3128 per-bucket (row,slice) bins

// column-split spmm: 4 splits of 16 cols; per-split Y region = 3.2MB <= 4MB L2
#define NSPL 4

// flags: [0] edge_nz  [1] emb_outl

__global__ void k_flags0(int* f, int* bcnt) {
    int t = threadIdx.x;
    if (t < 16) f[t] = 0;
    bcnt[t] = 0;
}

// fused vectorized input census, MLP-4 unrolled, block-reduced atomics.
// Reads the SAME byte ranges / same per-u16 predicate as before.
__global__ void __launch_bounds__(256) k_scan(const uint4* __restrict__ edge4,
                                              const uint4* __restrict__ emb4,
                                              int* __restrict__ fl) {
    __shared__ int red[256];
    __shared__ int rodd[256];
    int t = threadIdx.x;
    int gid = blockIdx.x * 256 + t;
    int step = gridDim.x * 256;

    // edge: words [0, 2*N_EDGES) as uint4; odd words are .y/.w
    unsigned odd = 0;
    const int NV_E = (2 * N_EDGES) / 4;        // 1,600,000 vecs
    int i = gid;
    for (; i + 3 * step < NV_E; i += 4 * step) {
        uint4 v0 = edge4[i];
        uint4 v1 = edge4[i + step];
        uint4 v2 = edge4[i + 2 * step];
        uint4 v3 = edge4[i + 3 * step];
        odd |= v0.y | v0.w | v1.y | v1.w | v2.y | v2.w | v3.y | v3.w;
    }
    for (; i < NV_E; i += step) {
        uint4 v = edge4[i];
        odd |= v.y | v.w;
    }

    // emb: first ND u16 as uint4 (8 u16 each)
    int local = 0;
    const int NV_M = ND / 8;                   // 800,000 vecs
#define CEN8(v)                                                          \
    {                                                                    \
        unsigned b;                                                      \
        b = ((v).x >> 8)  & 0x7f; if (b < 0x2e || b > 0x41) local++;     \
        b = ((v).x >> 24) & 0x7f; if (b < 0x2e || b > 0x41) local++;     \
        b = ((v).y >> 8)  & 0x7f; if (b < 0x2e || b > 0x41) local++;     \
        b = ((v).y >> 24) & 0x7f; if (b < 0x2e || b > 0x41) local++;     \
        b = ((v).z >> 8)  & 0x7f; if (b < 0x2e || b > 0x41) local++;     \
        b = ((v).z >> 24) & 0x7f; if (b < 0x2e || b > 0x41) local++;     \
        b = ((v).w >> 8)  & 0x7f; if (b < 0x2e || b > 0x41) local++;     \
        b = ((v).w >> 24) & 0x7f; if (b < 0x2e || b > 0x41) local++;     \
    }
    i = gid;
    for (; i + 3 * step < NV_M; i += 4 * step) {
        uint4 v0 = emb4[i];
        uint4 v1 = emb4[i + step];
        uint4 v2 = emb4[i + 2 * step];
        uint4 v3 = emb4[i + 3 * step];
        CEN8(v0); CEN8(v1); CEN8(v2); CEN8(v3);
    }
    for (; i < NV_M; i += step) {
        uint4 v = emb4[i];
        CEN8(v);
    }
#undef CEN8

    red[t] = local;
    rodd[t] = (odd != 0);
    __syncthreads();
    for (int s2 = 128; s2 > 0; s2 >>= 1) {
        if (t < s2) { red[t] += red[t + s2]; rodd[t] |= rodd[t + s2]; }
        __syncthreads();
    }
    if (t == 0) {
        if (red[0]) atomicAdd(&fl[1], red[0]);
        if (rodd[0]) atomicOr(&fl[0], 1);
    }
}

__device__ __forceinline__ int is_i64(const int* fl) { return fl[0] == 0; }
__device__ __forceinline__ int rd_src(const int* e, int i64, int k) {
    return i64 ? e[2 * k] : e[k];
}
__device__ __forceinline__ int rd_dst(const int* e, int i64, int k) {
    return i64 ? e[2 * (N_EDGES + k)] : e[N_EDGES + k];
}
__device__ __forceinline__ int clampid(int v) {
    return (v < 0) ? 0 : ((v >= N_NODES) ? (N_NODES - 1) : v);
}
__device__ __forceinline__ float rd_emb(const void* emb, const int* fl, int i) {
    if (fl[1] < (ND / 16)) return __bfloat162float(((const bf16*)emb)[i]);
    return ((const float*)emb)[i];
}

// ---- coarse bucket counts (LDS hist, 256 bins), uint4 dst-half loads ----
__global__ void __launch_bounds__(256) k_bcnt(const int* __restrict__ edge,
                                              const int* __restrict__ fl,
                                              int* __restrict__ bcnt) {
    __shared__ int h[PNB];
    int t = threadIdx.x;
    h[t] = 0;
    __syncthreads();
    const uint4* e4 = (const uint4*)edge;
    int gid = blockIdx.x * 256 + t;
    int step = gridDim.x * 256;
    if (is_i64(fl)) {
        const int base = N_EDGES / 2;          // dst half: word 2*N_EDGES -> vec idx
        const int nv   = N_EDGES / 2;          // 1.6M vecs (2 edges each)
        for (int i = gid; i < nv; i += step) {
            uint4 v = e4[base + i];
            atomicAdd(&h[clampid((int)v.x) / BSZ], 1);
            atomicAdd(&h[clampid((int)v.z) / BSZ], 1);
        }
    } else {
        const int base = N_EDGES / 4;          // dst half at word N_EDGES
        const int nv   = N_EDGES / 4;          // 800K vecs (4 edges each)
        for (int i = gid; i < nv; i += step) {
            uint4 v = e4[base + i];
            atomicAdd(&h[clampid((int)v.x) / BSZ], 1);
            atomicAdd(&h[clampid((int)v.y) / BSZ], 1);
            atomicAdd(&h[clampid((int)v.z) / BSZ], 1);
            atomicAdd(&h[clampid((int)v.w) / BSZ], 1);
        }
    }
    __syncthreads();
    if (h[t]) atomicAdd(&bcnt[t], h[t]);
}

// ---- parallel exclusive scan of bucket counts (1 block) ----
__global__ void __launch_bounds__(256) k_bscan(const int* __restrict__ bcnt,
                                               int* __restrict__ bbase,
                                               int* __restrict__ bcur) {
    __shared__ int sb[PNB];
    int t = threadIdx.x;
    int c = bcnt[t];
    sb[t] = c;
    __syncthreads();
    for (int off = 1; off < PNB; off <<= 1) {
        int v = (t >= off) ? sb[t - off] : 0;
        __syncthreads();
        sb[t] += v;
        __syncthreads();
    }
    int ex = sb[t] - c;
    bbase[t] = ex;
    bcur[t] = ex;
    if (t == PNB - 1) bbase[PNB] = sb[t];
}

// ---- partition edges into dst-buckets, LDS counting sort per 4096-edge block ----
__global__ void __launch_bounds__(256) k_part(const int* __restrict__ edge,
                                              const int* __restrict__ fl,
                                              int* __restrict__ bcur,
                                              uint2* __restrict__ pairs) {
    __shared__ int h[PNB];
    __shared__ int excl[PNB];
    __shared__ int gbase[PNB];
    __shared__ int lcur[PNB];
    __shared__ uint2 st[EPB];
    __shared__ unsigned char binof[EPB];
    int t = threadIdx.x;
    int e0 = blockIdx.x * EPB;
    int nval = N_EDGES - e0;
    if (nval > EPB) nval = EPB;
    int i64 = is_i64(fl);

    h[t] = 0;
    __syncthreads();
    for (int k = t; k < nval; k += 256) {
        int d = clampid(rd_dst(edge, i64, e0 + k));
        atomicAdd(&h[d / BSZ], 1);
    }
    __syncthreads();
    int c = h[t];
    excl[t] = c;
    __syncthreads();
    for (int off = 1; off < 256; off <<= 1) {
        int v = (t >= off) ? excl[t - off] : 0;
        __syncthreads();
        excl[t] += v;
        __syncthreads();
    }
    int myexcl = excl[t] - c;
    __syncthreads();
    excl[t] = myexcl;
    gbase[t] = (c > 0) ? atomicAdd(&bcur[t], c) : 0;
    lcur[t] = myexcl;
    __syncthreads();
    for (int k = t; k < nval; k += 256) {
        int s = clampid(rd_src(edge, i64, e0 + k));
        int d = clampid(rd_dst(edge, i64, e0 + k));
        int b = d / BSZ;
        int lp = atomicAdd(&lcur[b], 1);
        st[lp] = make_uint2((unsigned)s, (unsigned)d);
        binof[lp] = (unsigned char)b;
    }
    __syncthreads();
    for (int k = t; k < nval; k += 256) {
        int b = binof[k];
        pairs[gbase[b] + (k - excl[b])] = st[k];
    }
}

// ---- fused: per-(row,slice) hist -> scan -> rowptr2/dis emit -> place ----
__global__ void __launch_bounds__(1024) k_build(const uint2* __restrict__ pairs,
                                                const int* __restrict__ bbase,
                                                int* __restrict__ rp2,
                                                float* __restrict__ dis,
                                                int* __restrict__ csr) {
    __shared__ int hh[R8];      // (row,slice) counts -> within-row excl -> cursors
    __shared__ int rt[512];     // row-total scan
    int b = blockIdx.x;
    int t = threadIdx.x;
    int base = b * BSZ;
    for (int i = t; i < R8; i += 1024) hh[i] = 0;
    __syncthreads();
    int beg = bbase[b], end = bbase[b + 1];
    for (int i = beg + t; i < end; i += 1024) {
        uint2 p = pairs[i];
        int r = (int)p.y - base;
        int s = (int)p.x / SLW;
        atomicAdd(&hh[r * NSL + s], 1);
    }
    __syncthreads();
    int rtot = 0;
    if (t < BSZ) {
        int o = 0;
        for (int k = 0; k < NSL; k++) {
            int cc = hh[t * NSL + k];
            hh[t * NSL + k] = o;
            o += cc;
        }
        rtot = o;
    }
    if (t < 512) rt[t] = (t < BSZ) ? rtot : 0;
    __syncthreads();
    for (int off = 1; off < 512; off <<= 1) {
        int v = 0;
        if (t < 512 && t >= off) v = rt[t - off];
        __syncthreads();
        if (t < 512 && t >= off) rt[t] += v;
        __syncthreads();
    }
    if (t < BSZ) {
        int gb = beg + (rt[t] - rtot);   // global row start
        int n = base + t;
        if (n < N_NODES) {
            dis[n] = (rtot > 0) ? rsqrtf((float)rtot) : 0.0f;
            for (int k = 0; k < NSL; k++) rp2[n * NSL + k] = gb + hh[t * NSL + k];
            if (n == N_NODES - 1) rp2[N_NODES * NSL] = N_EDGES;  // sentinel
        }
        for (int k = 0; k < NSL; k++) hh[t * NSL + k] += gb;
    }
    __syncthreads();
    for (int i = beg + t; i < end; i += 1024) {
        uint2 p = pairs[i];
        int r = (int)p.y - base;
        int s = (int)p.x / SLW;
        int pos = atomicAdd(&hh[r * NSL + s], 1);
        csr[pos] = (int)p.x;
    }
}

// out (fp32, = d_out) = emb; Y0 = bf16(dis ⊙ emb) in SPLIT-MAJOR layout:
// Y[split][node][16 cols], split = col>>4 — each split region is 3.2MB.
__global__ void k_init(const void* __restrict__ emb, const int* __restrict__ fl,
                       const float* __restrict__ dis,
                       float* __restrict__ out, bf16* __restrict__ Y) {
    int i = blockIdx.x * blockDim.x + threadIdx.x;
    if (i < ND) {
        float v = rd_emb(emb, fl, i);
        out[i] = v;
        int n = i >> 6, cc = i & 63;
        Y[(size_t)(cc >> 4) * (N_NODES * 16) + n * 16 + (cc & 15)] =
            __float2bfloat16(dis[n] * v);
    }
}

#define GATHER4(SRC)                                                     \
    {                                                                    \
        uint2 v = *(const uint2*)(Ys + (SRC) * 8 + c * 2);               \
        a0 += __uint_as_float(v.x << 16);                                \
        a1 += __uint_as_float(v.x & 0xffff0000u);                        \
        a2 += __uint_as_float(v.y << 16);                                \
        a3 += __uint_as_float(v.y & 0xffff0000u);                        \
    }

// column-split SpMM, all 4 splits in ONE dispatch per layer.
// XCD-aware mapping: xcd = bid&7, split = xcd>>1 — each split is served by
// exactly 2 XCDs, so each XCD's L2 holds only its split's 3.2MB Y region,
// and csr is read once per layer (shared via L3 across splits).
// Per wave: 4 rows (16 lanes each: 4 edge slots x 4 col-groups).
// Inner step 16 edges => 4 independent csr loads -> 4 gathers in flight.
__global__ void __launch_bounds__(256) k_spmm(
        const int* __restrict__ rp2, const int* __restrict__ csr,
        const float* __restrict__ dis, const bf16* __restrict__ Yin,
        float* __restrict__ out, bf16* __restrict__ Yout, int last) {
    int bid = blockIdx.x;
    int xcd = bid & 7;
    int s = xcd >> 1;                      // split 0..3
    int rowblk = (bid >> 3) * 2 + (xcd & 1);   // 0..6249
    int wave = threadIdx.x >> 6;
    int lane = threadIdx.x & 63;
    int g = lane >> 4;          // row group within wave
    int l = lane & 15;
    int e = l >> 2;             // 4 edge slots
    int c = l & 3;              // col group (4 bf16 = 8B)
    int n = rowblk * 16 + wave * 4 + g;
    if (n >= N_NODES) return;
    int beg = rp2[n * NSL];
    int end = rp2[(n + 1) * NSL];          // sentinel covers n = N_NODES-1
    const unsigned* Ys = (const unsigned*)Yin + (size_t)s * (N_NODES * 8);
    float a0 = 0.f, a1 = 0.f, a2 = 0.f, a3 = 0.f;
    int j = beg;
    for (; j + 16 <= end; j += 16) {
        int s0 = csr[j + e];
        int s1 = csr[j + 4 + e];
        int s2 = csr[j + 8 + e];
        int s3 = csr[j + 12 + e];
        GATHER4(s0);
        GATHER4(s1);
        GATHER4(s2);
        GATHER4(s3);
    }
    for (; j + 8 <= end; j += 8) {
        int s0 = csr[j + e];
        int s1 = csr[j + 4 + e];
        GATHER4(s0);
        GATHER4(s1);
    }
    if (j + e < end)     { int sv = csr[j + e];     GATHER4(sv); }
    if (j + 4 + e < end) { int sv = csr[j + 4 + e]; GATHER4(sv); }
    // reduce across the 4 edge slots (stays inside each 16-lane row group)
    a0 += __shfl_xor(a0, 4); a0 += __shfl_xor(a0, 8);
    a1 += __shfl_xor(a1, 4); a1 += __shfl_xor(a1, 8);
    a2 += __shfl_xor(a2, 4); a2 += __shfl_xor(a2, 8);
    a3 += __shfl_xor(a3, 4); a3 += __shfl_xor(a3, 8);
    if (e == 0) {               // 4 lanes per row group, l == c
        float dn = dis[n];
        float x0 = dn * a0, x1 = dn * a1, x2 = dn * a2, x3 = dn * a3;
        int i4 = n * 16 + s * 4 + c;       // float4 idx: cols s*16 + c*4 ..
        f32x4 o = __builtin_nontemporal_load((const f32x4*)out + i4);
        if (last) {
            o.x = (o.x + x0) * 0.25f;
            o.y = (o.y + x1) * 0.25f;
            o.z = (o.z + x2) * 0.25f;
            o.w = (o.w + x3) * 0.25f;
            __builtin_nontemporal_store(o, (f32x4*)out + i4);
        } else {
            o.x += x0; o.y += x1; o.z += x2; o.w += x3;
            __builtin_nontemporal_store(o, (f32x4*)out + i4);
            bf16 t0 = __float2bfloat16(dn * x0);
            bf16 t1 = __float2bfloat16(dn * x1);
            bf16 t2 = __float2bfloat16(dn * x2);
            bf16 t3 = __float2bfloat16(dn * x3);
            u16x4 yv;
            yv.x = *(unsigned short*)&t0;
            yv.y = *(unsigned short*)&t1;
            yv.z = *(unsigned short*)&t2;
            yv.w = *(unsigned short*)&t3;
            // split-major Yout: region s, node n, col-group c
            __builtin_nontemporal_store(
                yv, (u16x4*)Yout + (size_t)s * (N_NODES * 4) + n * 4 + c);
        }
    }
}

__global__ void k_fill42(float* __restrict__ o) {
    int i = blockIdx.x * blockDim.x + threadIdx.x;
    if (i < ND) o[i] = 42.0f;   // signature: ws too small for CSR layout
}

extern "C" void kernel_launch(void* const* d_in, const int* in_sizes, int n_in,
                              void* d_out, int out_size, void* d_ws, size_t ws_size,
                              hipStream_t stream) {
    const void* emb = d_in[0];
    const int* edge = (const int*)d_in[1];
    float* out = (float*)d_out;

    const int B = 256;
    const int gND = (ND + B - 1) / B;           // 25000
    const int gP  = (N_EDGES + EPB - 1) / EPB;  // 782 partition blocks
    const int gS  = 25000;                      // 4 splits x 6250 row-blocks

    char* ws = (char*)d_ws;
    int* fl = (int*)ws;
    size_t off = 256;
    const size_t off_dis   = off;  off += (size_t)N_NODES * 4;
    const size_t off_rp2   = off;  off += (size_t)(N_NODES * NSL + 8) * 4;
    const size_t off_bcnt  = off;  off += 1024;
    const size_t off_bbase = off;  off += 1056;
    const size_t off_bcur  = off;  off += 1024;
    const size_t off_csr   = off;  off += (size_t)N_EDGES * 4;
    const size_t off_Y0    = off;  off += (size_t)ND * 2;
    const size_t off_Y1    = off;  off += (size_t)ND * 2;
    const size_t need = off;                    // ~42.0 MB

    if (ws_size < need) {
        k_fill42<<<gND, B, 0, stream>>>(out);
        return;
    }

    float* dis   = (float*)(ws + off_dis);
    int*   rp2   = (int*)(ws + off_rp2);
    int*   bcnt  = (int*)(ws + off_bcnt);
    int*   bbase = (int*)(ws + off_bbase);
    int*   bcur  = (int*)(ws + off_bcur);
    int*   csr   = (int*)(ws + off_csr);
    uint2* pairs = (uint2*)(ws + off_Y0);       // 25.6MB, reuses Y0+Y1 (dead until k_init)
    bf16*  Y0    = (bf16*)(ws + off_Y0);
    bf16*  Y1    = (bf16*)(ws + off_Y1);

    k_flags0<<<1, 256, 0, stream>>>(fl, bcnt);
    k_scan<<<512, B, 0, stream>>>((const uint4*)edge, (const uint4*)emb, fl);

    // bucketed CSR build
    k_bcnt<<<1024, B, 0, stream>>>(edge, fl, bcnt);
    k_bscan<<<1, 256, 0, stream>>>(bcnt, bbase, bcur);
    k_part<<<gP, B, 0, stream>>>(edge, fl, bcur, pairs);
    k_build<<<PNB, 1024, 0, stream>>>(pairs, bbase, rp2, dis, csr);

    k_init<<<gND, B, 0, stream>>>(emb, fl, dis, out, Y0);

    k_spmm<<<gS, B, 0, stream>>>(rp2, csr, dis, Y0, out, Y1, 0);
    k_spmm<<<gS, B, 0, stream>>>(rp2, csr, dis, Y1, out, Y0, 0);
    k_spmm<<<gS, B, 0, stream>>>(rp2, csr, dis, Y0, out, Y1, 1);
}

// Round 9
// 473.415 us; speedup vs baseline: 2.4257x; 1.0652x over previous
//
#include <hip/hip_runtime.h>
#include <hip/hip_bf16.h>

typedef __hip_bfloat16 bf16;
typedef float          f32x4 __attribute__((ext_vector_type(4)));
typedef unsigned short u16x4 __attribute__((ext_vector_type(4)));

#define N_NODES  100000
#define EMBED    64
#define N_EDGES  3200000
#define ND       6400000
#define N_LAYERS 3

// bucketed CSR build
#define PNB  256            // number of dst buckets
#define BSZ  391            // nodes per bucket (256*391 = 100096 >= N_NODES)
#define EPB  4096            // edges per partition block (even in every block)
#define NSL  8              // src slices inside a row (grouping within rows)
#define SLW  12512          // slice width
#define R8   (BSZ * NSL)    // 3128 per-bucket (row,slice) bins

// column-split spmm: 4 splits of 16 cols; per-split Y region = 3.2MB <= 4MB L2
#define NSPL 4

// flags: [1] emb_outl (edge dtype now resolved host-side via in_sizes)

__global__ void k_flags0(int* f, int* bcnt) {
    int t = threadIdx.x;
    if (t < 16) f[t] = 0;
    bcnt[t] = 0;
}

__device__ __forceinline__ int rd_src(const int* e, int i64, int k) {
    return i64 ? e[2 * k] : e[k];
}
__device__ __forceinline__ int rd_dst(const int* e, int i64, int k) {
    return i64 ? e[2 * (N_EDGES + k)] : e[N_EDGES + k];
}
__device__ __forceinline__ int clampid(int v) {
    return (v < 0) ? 0 : ((v >= N_NODES) ? (N_NODES - 1) : v);
}

// fused: emb census (block-reduced) + coarse dst-bucket histogram.
__global__ void __launch_bounds__(256) k_scanb(const int* __restrict__ edge,
                                               const uint4* __restrict__ emb4,
                                               int i64, int* __restrict__ fl,
                                               int* __restrict__ bcnt) {
    __shared__ int h[PNB];
    __shared__ int red[256];
    int t = threadIdx.x;
    int gid = blockIdx.x * 256 + t;
    int step = gridDim.x * 256;
    h[t] = 0;
    __syncthreads();

    // emb census: first ND u16 as uint4 (8 u16 each), MLP-4
    int local = 0;
    const int NV_M = ND / 8;
#define CEN8(v)                                                          \
    {                                                                    \
        unsigned b;                                                      \
        b = ((v).x >> 8)  & 0x7f; if (b < 0x2e || b > 0x41) local++;     \
        b = ((v).x >> 24) & 0x7f; if (b < 0x2e || b > 0x41) local++;     \
        b = ((v).y >> 8)  & 0x7f; if (b < 0x2e || b > 0x41) local++;     \
        b = ((v).y >> 24) & 0x7f; if (b < 0x2e || b > 0x41) local++;     \
        b = ((v).z >> 8)  & 0x7f; if (b < 0x2e || b > 0x41) local++;     \
        b = ((v).z >> 24) & 0x7f; if (b < 0x2e || b > 0x41) local++;     \
        b = ((v).w >> 8)  & 0x7f; if (b < 0x2e || b > 0x41) local++;     \
        b = ((v).w >> 24) & 0x7f; if (b < 0x2e || b > 0x41) local++;     \
    }
    int i = gid;
    for (; i + 3 * step < NV_M; i += 4 * step) {
        uint4 v0 = emb4[i];
        uint4 v1 = emb4[i + step];
        uint4 v2 = emb4[i + 2 * step];
        uint4 v3 = emb4[i + 3 * step];
        CEN8(v0); CEN8(v1); CEN8(v2); CEN8(v3);
    }
    for (; i < NV_M; i += step) {
        uint4 v = emb4[i];
        CEN8(v);
    }
#undef CEN8

    // dst-bucket histogram (uint4 loads)
    const uint4* e4 = (const uint4*)edge;
    if (i64) {
        const int base = N_EDGES / 2;          // dst half starts at word 2*N_EDGES
        const int nv   = N_EDGES / 2;          // 2 edges per vec (x,z)
        for (int k = gid; k < nv; k += step) {
            uint4 v = e4[base + k];
            atomicAdd(&h[clampid((int)v.x) / BSZ], 1);
            atomicAdd(&h[clampid((int)v.z) / BSZ], 1);
        }
    } else {
        const int base = N_EDGES / 4;          // dst half at word N_EDGES
        const int nv   = N_EDGES / 4;          // 4 edges per vec
        for (int k = gid; k < nv; k += step) {
            uint4 v = e4[base + k];
            atomicAdd(&h[clampid((int)v.x) / BSZ], 1);
            atomicAdd(&h[clampid((int)v.y) / BSZ], 1);
            atomicAdd(&h[clampid((int)v.z) / BSZ], 1);
            atomicAdd(&h[clampid((int)v.w) / BSZ], 1);
        }
    }

    red[t] = local;
    __syncthreads();                 // also fences all LDS hist atomics
    for (int s2 = 128; s2 > 0; s2 >>= 1) {
        if (t < s2) red[t] += red[t + s2];
        __syncthreads();
    }
    if (t == 0 && red[0]) atomicAdd(&fl[1], red[0]);
    if (h[t]) atomicAdd(&bcnt[t], h[t]);
}

// ---- parallel exclusive scan of bucket counts (1 block) ----
__global__ void __launch_bounds__(256) k_bscan(const int* __restrict__ bcnt,
                                               int* __restrict__ bbase,
                                               int* __restrict__ bcur) {
    __shared__ int sb[PNB];
    int t = threadIdx.x;
    int c = bcnt[t];
    sb[t] = c;
    __syncthreads();
    for (int off = 1; off < PNB; off <<= 1) {
        int v = (t >= off) ? sb[t - off] : 0;
        __syncthreads();
        sb[t] += v;
        __syncthreads();
    }
    int ex = sb[t] - c;
    bbase[t] = ex;
    bcur[t] = ex;
    if (t == PNB - 1) bbase[PNB] = sb[t];
}

// ---- partition edges into dst-buckets, LDS counting sort per 4096-edge block ----
__global__ void __launch_bounds__(256) k_part(const int* __restrict__ edge,
                                              int i64,
                                              int* __restrict__ bcur,
                                              uint2* __restrict__ pairs) {
    __shared__ int h[PNB];
    __shared__ int excl[PNB];
    __shared__ int gbase[PNB];
    __shared__ int lcur[PNB];
    __shared__ uint2 st[EPB];
    __shared__ unsigned char binof[EPB];
    int t = threadIdx.x;
    int e0 = blockIdx.x * EPB;
    int nval = N_EDGES - e0;
    if (nval > EPB) nval = EPB;
    const uint4* e4 = (const uint4*)edge;

    h[t] = 0;
    __syncthreads();
    // count pass
    if (i64) {
        int half = nval >> 1;                       // nval always even
        for (int m = t; m < half; m += 256) {
            uint4 v = e4[(size_t)(N_EDGES / 2) + (e0 >> 1) + m];
            atomicAdd(&h[clampid((int)v.x) / BSZ], 1);
            atomicAdd(&h[clampid((int)v.z) / BSZ], 1);
        }
    } else {
        for (int k = t; k < nval; k += 256) {
            int d = clampid(rd_dst(edge, 0, e0 + k));
            atomicAdd(&h[d / BSZ], 1);
        }
    }
    __syncthreads();
    int c = h[t];
    excl[t] = c;
    __syncthreads();
    for (int off = 1; off < 256; off <<= 1) {
        int v = (t >= off) ? excl[t - off] : 0;
        __syncthreads();
        excl[t] += v;
        __syncthreads();
    }
    int myexcl = excl[t] - c;
    __syncthreads();
    excl[t] = myexcl;
    gbase[t] = (c > 0) ? atomicAdd(&bcur[t], c) : 0;
    lcur[t] = myexcl;
    __syncthreads();
    // scatter into LDS, ordered by bucket
    if (i64) {
        int half = nval >> 1;
        for (int m = t; m < half; m += 256) {
            uint4 vs = e4[(e0 >> 1) + m];
            uint4 vd = e4[(size_t)(N_EDGES / 2) + (e0 >> 1) + m];
            int s0 = clampid((int)vs.x), d0 = clampid((int)vd.x);
            int b0 = d0 / BSZ;
            int lp0 = atomicAdd(&lcur[b0], 1);
            st[lp0] = make_uint2((unsigned)s0, (unsigned)d0);
            binof[lp0] = (unsigned char)b0;
            int s1 = clampid((int)vs.z), d1 = clampid((int)vd.z);
            int b1 = d1 / BSZ;
            int lp1 = atomicAdd(&lcur[b1], 1);
            st[lp1] = make_uint2((unsigned)s1, (unsigned)d1);
            binof[lp1] = (unsigned char)b1;
        }
    } else {
        for (int k = t; k < nval; k += 256) {
            int s = clampid(rd_src(edge, 0, e0 + k));
            int d = clampid(rd_dst(edge, 0, e0 + k));
            int b = d / BSZ;
            int lp = atomicAdd(&lcur[b], 1);
            st[lp] = make_uint2((unsigned)s, (unsigned)d);
            binof[lp] = (unsigned char)b;
        }
    }
    __syncthreads();
    // flush: runs of same-bucket pairs -> contiguous global spans (coalesced)
    for (int k = t; k < nval; k += 256) {
        int b = binof[k];
        pairs[gbase[b] + (k - excl[b])] = st[k];
    }
}

// ---- fused: per-(row,slice) hist -> scan -> rowptr2/dis emit -> place ----
__global__ void __launch_bounds__(1024) k_build(const uint2* __restrict__ pairs,
                                                const int* __restrict__ bbase,
                                                int* __restrict__ rp2,
                                                float* __restrict__ dis,
                                                int* __restrict__ csr) {
    __shared__ int hh[R8];      // (row,slice) counts -> within-row excl -> cursors
    __shared__ int rt[512];     // row-total scan
    int b = blockIdx.x;
    int t = threadIdx.x;
    int base = b * BSZ;
    for (int i = t; i < R8; i += 1024) hh[i] = 0;
    __syncthreads();
    int beg = bbase[b], end = bbase[b + 1];
    for (int i = beg + t; i < end; i += 1024) {
        uint2 p = pairs[i];
        int r = (int)p.y - base;
        int s = (int)p.x / SLW;
        atomicAdd(&hh[r * NSL + s], 1);
    }
    __syncthreads();
    int rtot = 0;
    if (t < BSZ) {
        int o = 0;
        for (int k = 0; k < NSL; k++) {
            int cc = hh[t * NSL + k];
            hh[t * NSL + k] = o;
            o += cc;
        }
        rtot = o;
    }
    if (t < 512) rt[t] = (t < BSZ) ? rtot : 0;
    __syncthreads();
    for (int off = 1; off < 512; off <<= 1) {
        int v = 0;
        if (t < 512 && t >= off) v = rt[t - off];
        __syncthreads();
        if (t < 512 && t >= off) rt[t] += v;
        __syncthreads();
    }
    if (t < BSZ) {
        int gb = beg + (rt[t] - rtot);   // global row start
        int n = base + t;
        if (n < N_NODES) {
            dis[n] = (rtot > 0) ? rsqrtf((float)rtot) : 0.0f;
            for (int k = 0; k < NSL; k++) rp2[n * NSL + k] = gb + hh[t * NSL + k];
            if (n == N_NODES - 1) rp2[N_NODES * NSL] = N_EDGES;  // sentinel
        }
        for (int k = 0; k < NSL; k++) hh[t * NSL + k] += gb;
    }
    __syncthreads();
    for (int i = beg + t; i < end; i += 1024) {
        uint2 p = pairs[i];
        int r = (int)p.y - base;
        int s = (int)p.x / SLW;
        int pos = atomicAdd(&hh[r * NSL + s], 1);
        csr[pos] = (int)p.x;
    }
}

// out (fp32, = d_out) = emb; Y0 = bf16(dis ⊙ emb) in SPLIT-MAJOR layout.
// 8 elems per thread, f32x4 loads/stores on the fp32 fast path.
__global__ void __launch_bounds__(256) k_init(const void* __restrict__ emb,
                                              const int* __restrict__ fl,
                                              const float* __restrict__ dis,
                                              float* __restrict__ out,
                                              bf16* __restrict__ Y) {
    int idx = blockIdx.x * 256 + threadIdx.x;      // 800K threads
    if (idx >= ND / 8) return;
    int n = idx >> 3;
    int g = idx & 7;                               // 8-col group
    float dn = dis[n];
    float f[8];
    if (fl[1] < (ND / 16)) {                       // bf16 emb (unlikely path)
        const bf16* eb = (const bf16*)emb + (size_t)idx * 8;
        for (int k = 0; k < 8; k++) f[k] = __bfloat162float(eb[k]);
    } else {
        const f32x4* e4 = (const f32x4*)emb + (size_t)idx * 2;
        f32x4 a = e4[0], b = e4[1];
        f[0] = a.x; f[1] = a.y; f[2] = a.z; f[3] = a.w;
        f[4] = b.x; f[5] = b.y; f[6] = b.z; f[7] = b.w;
    }
    f32x4* o4 = (f32x4*)out + (size_t)idx * 2;
    f32x4 oa, ob;
    oa.x = f[0]; oa.y = f[1]; oa.z = f[2]; oa.w = f[3];
    ob.x = f[4]; ob.y = f[5]; ob.z = f[6]; ob.w = f[7];
    o4[0] = oa; o4[1] = ob;
    // split-major Y: split s = g>>1, within-split col = (g&1)*8 + k
    int s = g >> 1;
    u16x4* yp = (u16x4*)Y + (size_t)s * (N_NODES * 4) + n * 4 + (g & 1) * 2;
    u16x4 y0, y1;
    bf16 tb;
    tb = __float2bfloat16(dn * f[0]); y0.x = *(unsigned short*)&tb;
    tb = __float2bfloat16(dn * f[1]); y0.y = *(unsigned short*)&tb;
    tb = __float2bfloat16(dn * f[2]); y0.z = *(unsigned short*)&tb;
    tb = __float2bfloat16(dn * f[3]); y0.w = *(unsigned short*)&tb;
    tb = __float2bfloat16(dn * f[4]); y1.x = *(unsigned short*)&tb;
    tb = __float2bfloat16(dn * f[5]); y1.y = *(unsigned short*)&tb;
    tb = __float2bfloat16(dn * f[6]); y1.z = *(unsigned short*)&tb;
    tb = __float2bfloat16(dn * f[7]); y1.w = *(unsigned short*)&tb;
    yp[0] = y0; yp[1] = y1;
}

#define GATHER8(SRC)                                                     \
    {                                                                    \
        uint4 v = Ys[(size_t)(SRC) * 2 + c];                             \
        a0 += __uint_as_float(v.x << 16);                                \
        a1 += __uint_as_float(v.x & 0xffff0000u);                        \
        a2 += __uint_as_float(v.y << 16);                                \
        a3 += __uint_as_float(v.y & 0xffff0000u);                        \
        a4 += __uint_as_float(v.z << 16);                                \
        a5 += __uint_as_float(v.z & 0xffff0000u);                        \
        a6 += __uint_as_float(v.w << 16);                                \
        a7 += __uint_as_float(v.w & 0xffff0000u);                        \
    }

// column-split SpMM, all 4 splits in ONE dispatch per layer.
// XCD mapping: xcd = bid&7, split = xcd>>1 (each split served by 2 XCDs).
// Per wave: 4 rows; per 16-lane row group: 8 edge slots x 2 col-groups of
// 16B (uint4 = 8 bf16). 32-edge main loop -> 4 csr + 4 gathers in flight
// covering 32 edges (2x edges per vmcnt slot vs round 8).
__global__ void __launch_bounds__(256) k_spmm(
        const int* __restrict__ rp2, const int* __restrict__ csr,
        const float* __restrict__ dis, const bf16* __restrict__ Yin,
        float* __restrict__ out, bf16* __restrict__ Yout, int last) {
    int bid = blockIdx.x;
    int xcd = bid & 7;
    int s = xcd >> 1;                          // split 0..3
    int rowblk = (bid >> 3) * 2 + (xcd & 1);   // 0..6249
    int wave = threadIdx.x >> 6;
    int lane = threadIdx.x & 63;
    int l = lane & 15;
    int e = l >> 1;             // 8 edge slots
    int c = l & 1;              // 2 col groups (16B each)
    int n = rowblk * 16 + wave * 4 + (lane >> 4);
    if (n >= N_NODES) return;
    int beg = rp2[n * NSL];
    int end = rp2[(n + 1) * NSL];              // sentinel covers last row
    const uint4* Ys = (const uint4*)Yin + (size_t)s * (N_NODES * 2);
    float a0 = 0.f, a1 = 0.f, a2 = 0.f, a3 = 0.f;
    float a4 = 0.f, a5 = 0.f, a6 = 0.f, a7 = 0.f;
    int j = beg;
    for (; j + 32 <= end; j += 32) {
        int s0 = csr[j + e];
        int s1 = csr[j + 8 + e];
        int s2 = csr[j + 16 + e];
        int s3 = csr[j + 24 + e];
        GATHER8(s0);
        GATHER8(s1);
        GATHER8(s2);
        GATHER8(s3);
    }
    if (j + 16 <= end) {
        int s0 = csr[j + e];
        int s1 = csr[j + 8 + e];
        GATHER8(s0);
        GATHER8(s1);
        j += 16;
    }
    if (j + 8 <= end) {
        int s0 = csr[j + e];
        GATHER8(s0);
        j += 8;
    }
    if (j + e < end) {
        int sv = csr[j + e];
        GATHER8(sv);
    }
    // reduce across the 8 edge slots (xor bits 1,2,3 keep c and row group)
    a0 += __shfl_xor(a0, 2); a0 += __shfl_xor(a0, 4); a0 += __shfl_xor(a0, 8);
    a1 += __shfl_xor(a1, 2); a1 += __shfl_xor(a1, 4); a1 += __shfl_xor(a1, 8);
    a2 += __shfl_xor(a2, 2); a2 += __shfl_xor(a2, 4); a2 += __shfl_xor(a2, 8);
    a3 += __shfl_xor(a3, 2); a3 += __shfl_xor(a3, 4); a3 += __shfl_xor(a3, 8);
    a4 += __shfl_xor(a4, 2); a4 += __shfl_xor(a4, 4); a4 += __shfl_xor(a4, 8);
    a5 += __shfl_xor(a5, 2); a5 += __shfl_xor(a5, 4); a5 += __shfl_xor(a5, 8);
    a6 += __shfl_xor(a6, 2); a6 += __shfl_xor(a6, 4); a6 += __shfl_xor(a6, 8);
    a7 += __shfl_xor(a7, 2); a7 += __shfl_xor(a7, 4); a7 += __shfl_xor(a7, 8);
    if (e == 0) {               // 2 lanes per row group (l == c)
        float dn = dis[n];
        int i8 = n * 16 + s * 4 + c * 2;       // f32x4 index
        f32x4 oa = __builtin_nontemporal_load((const f32x4*)out + i8);
        f32x4 ob = __builtin_nontemporal_load((const f32x4*)out + i8 + 1);
        float x0 = dn * a0, x1 = dn * a1, x2 = dn * a2, x3 = dn * a3;
        float x4 = dn * a4, x5 = dn * a5, x6 = dn * a6, x7 = dn * a7;
        if (last) {
            oa.x = (oa.x + x0) * 0.25f; oa.y = (oa.y + x1) * 0.25f;
            oa.z = (oa.z + x2) * 0.25f; oa.w = (oa.w + x3) * 0.25f;
            ob.x = (ob.x + x4) * 0.25f; ob.y = (ob.y + x5) * 0.25f;
            ob.z = (ob.z + x6) * 0.25f; ob.w = (ob.w + x7) * 0.25f;
            __builtin_nontemporal_store(oa, (f32x4*)out + i8);
            __builtin_nontemporal_store(ob, (f32x4*)out + i8 + 1);
        } else {
            oa.x += x0; oa.y += x1; oa.z += x2; oa.w += x3;
            ob.x += x4; ob.y += x5; ob.z += x6; ob.w += x7;
            __builtin_nontemporal_store(oa, (f32x4*)out + i8);
            __builtin_nontemporal_store(ob, (f32x4*)out + i8 + 1);
            u16x4 y0, y1;
            bf16 tb;
            tb = __float2bfloat16(dn * x0); y0.x = *(unsigned short*)&tb;
            tb = __float2bfloat16(dn * x1); y0.y = *(unsigned short*)&tb;
            tb = __float2bfloat16(dn * x2); y0.z = *(unsigned short*)&tb;
            tb = __float2bfloat16(dn * x3); y0.w = *(unsigned short*)&tb;
            tb = __float2bfloat16(dn * x4); y1.x = *(unsigned short*)&tb;
            tb = __float2bfloat16(dn * x5); y1.y = *(unsigned short*)&tb;
            tb = __float2bfloat16(dn * x6); y1.z = *(unsigned short*)&tb;
            tb = __float2bfloat16(dn * x7); y1.w = *(unsigned short*)&tb;
            u16x4* yp = (u16x4*)Yout + (size_t)s * (N_NODES * 4) + n * 4 + c * 2;
            __builtin_nontemporal_store(y0, yp);
            __builtin_nontemporal_store(y1, yp + 1);
        }
    }
}

__global__ void k_fill42(float* __restrict__ o) {
    int i = blockIdx.x * blockDim.x + threadIdx.x;
    if (i < ND) o[i] = 42.0f;   // signature: ws too small for CSR layout
}

extern "C" void kernel_launch(void* const* d_in, const int* in_sizes, int n_in,
                              void* d_out, int out_size, void* d_ws, size_t ws_size,
                              hipStream_t stream) {
    const void* emb = d_in[0];
    const int* edge = (const int*)d_in[1];
    float* out = (float*)d_out;

    // host-side dtype resolution: int64 edge buffer = 2*E*8 bytes
    const long long i64_bytes = 2LL * N_EDGES * 8;
    int i64 = (in_sizes[1] >= (int)i64_bytes) ? 1 : 0;

    const int B = 256;
    const int gND = (ND + B - 1) / B;           // 25000
    const int gI  = (ND / 8 + B - 1) / B;       // 3125
    const int gP  = (N_EDGES + EPB - 1) / EPB;  // 782 partition blocks
    const int gS  = 25000;                      // 4 splits x 6250 row-blocks

    char* ws = (char*)d_ws;
    int* fl = (int*)ws;
    size_t off = 256;
    const size_t off_dis   = off;  off += (size_t)N_NODES * 4;
    const size_t off_rp2   = off;  off += (size_t)(N_NODES * NSL + 8) * 4;
    const size_t off_bcnt  = off;  off += 1024;
    const size_t off_bbase = off;  off += 1056;
    const size_t off_bcur  = off;  off += 1024;
    const size_t off_csr   = off;  off += (size_t)N_EDGES * 4;
    const size_t off_Y0    = off;  off += (size_t)ND * 2;
    const size_t off_Y1    = off;  off += (size_t)ND * 2;
    const size_t need = off;                    // ~42.0 MB

    if (ws_size < need) {
        k_fill42<<<gND, B, 0, stream>>>(out);
        return;
    }

    float* dis   = (float*)(ws + off_dis);
    int*   rp2   = (int*)(ws + off_rp2);
    int*   bcnt  = (int*)(ws + off_bcnt);
    int*   bbase = (int*)(ws + off_bbase);
    int*   bcur  = (int*)(ws + off_bcur);
    int*   csr   = (int*)(ws + off_csr);
    uint2* pairs = (uint2*)(ws + off_Y0);       // 25.6MB, reuses Y0+Y1 (dead until k_init)
    bf16*  Y0    = (bf16*)(ws + off_Y0);
    bf16*  Y1    = (bf16*)(ws + off_Y1);

    k_flags0<<<1, 256, 0, stream>>>(fl, bcnt);
    k_scanb<<<512, B, 0, stream>>>(edge, (const uint4*)emb, i64, fl, bcnt);

    // bucketed CSR build
    k_bscan<<<1, 256, 0, stream>>>(bcnt, bbase, bcur);
    k_part<<<gP, B, 0, stream>>>(edge, i64, bcur, pairs);
    k_build<<<PNB, 1024, 0, stream>>>(pairs, bbase, rp2, dis, csr);

    k_init<<<gI, B, 0, stream>>>(emb, fl, dis, out, Y0);

    k_spmm<<<gS, B, 0, stream>>>(rp2, csr, dis, Y0, out, Y1, 0);
    k_spmm<<<gS, B, 0, stream>>>(rp2, csr, dis, Y1, out, Y0, 0);
    k_spmm<<<gS, B, 0, stream>>>(rp2, csr, dis, Y0, out, Y1, 1);
}

// Round 10
// 445.841 us; speedup vs baseline: 2.5757x; 1.0618x over previous
//
#include <hip/hip_runtime.h>
#include <hip/hip_bf16.h>

typedef __hip_bfloat16 bf16;
typedef float          f32x4 __attribute__((ext_vector_type(4)));
typedef unsigned short u16x4 __attribute__((ext_vector_type(4)));

#define N_NODES  100000
#define EMBED    64
#define N_EDGES  3200000
#define ND       6400000
#define N_LAYERS 3

// bucketed CSR build
#define PNB  256            // number of dst buckets
#define BSZ  391            // nodes per bucket (256*391 = 100096 >= N_NODES)
#define EPB  4096           // edges per partition block (even in every block)

// flags: [1] emb_outl census (over first ND/8 u16s; threshold ND/128)

__global__ void k_flags0(int* f, int* bcnt) {
    int t = threadIdx.x;
    if (t < 16) f[t] = 0;
    bcnt[t] = 0;
}

__device__ __forceinline__ int rd_src(const int* e, int i64, int k) {
    return i64 ? e[2 * k] : e[k];
}
__device__ __forceinline__ int rd_dst(const int* e, int i64, int k) {
    return i64 ? e[2 * (N_EDGES + k)] : e[N_EDGES + k];
}
__device__ __forceinline__ int clampid(int v) {
    return (v < 0) ? 0 : ((v >= N_NODES) ? (N_NODES - 1) : v);
}

// fused: emb census (sampled, block-reduced) + coarse dst-bucket histogram.
__global__ void __launch_bounds__(256) k_scanb(const int* __restrict__ edge,
                                               const uint4* __restrict__ emb4,
                                               int i64, int* __restrict__ fl,
                                               int* __restrict__ bcnt) {
    __shared__ int h[PNB];
    __shared__ int red[256];
    int t = threadIdx.x;
    int gid = blockIdx.x * 256 + t;
    int step = gridDim.x * 256;
    h[t] = 0;
    __syncthreads();

    // emb census: first ND/8 u16s as uint4 (8 u16 each)
    int local = 0;
    const int NV_M = ND / 64;                  // 100,000 vecs
#define CEN8(v)                                                          \
    {                                                                    \
        unsigned b;                                                      \
        b = ((v).x >> 8)  & 0x7f; if (b < 0x2e || b > 0x41) local++;     \
        b = ((v).x >> 24) & 0x7f; if (b < 0x2e || b > 0x41) local++;     \
        b = ((v).y >> 8)  & 0x7f; if (b < 0x2e || b > 0x41) local++;     \
        b = ((v).y >> 24) & 0x7f; if (b < 0x2e || b > 0x41) local++;     \
        b = ((v).z >> 8)  & 0x7f; if (b < 0x2e || b > 0x41) local++;     \
        b = ((v).z >> 24) & 0x7f; if (b < 0x2e || b > 0x41) local++;     \
        b = ((v).w >> 8)  & 0x7f; if (b < 0x2e || b > 0x41) local++;     \
        b = ((v).w >> 24) & 0x7f; if (b < 0x2e || b > 0x41) local++;     \
    }
    for (int i = gid; i < NV_M; i += step) {
        uint4 v = emb4[i];
        CEN8(v);
    }
#undef CEN8

    // dst-bucket histogram (uint4 loads)
    const uint4* e4 = (const uint4*)edge;
    if (i64) {
        const int base = N_EDGES / 2;          // dst half starts at word 2*N_EDGES
        const int nv   = N_EDGES / 2;          // 2 edges per vec (x,z)
        for (int k = gid; k < nv; k += step) {
            uint4 v = e4[base + k];
            atomicAdd(&h[clampid((int)v.x) / BSZ], 1);
            atomicAdd(&h[clampid((int)v.z) / BSZ], 1);
        }
    } else {
        const int base = N_EDGES / 4;          // dst half at word N_EDGES
        const int nv   = N_EDGES / 4;          // 4 edges per vec
        for (int k = gid; k < nv; k += step) {
            uint4 v = e4[base + k];
            atomicAdd(&h[clampid((int)v.x) / BSZ], 1);
            atomicAdd(&h[clampid((int)v.y) / BSZ], 1);
            atomicAdd(&h[clampid((int)v.z) / BSZ], 1);
            atomicAdd(&h[clampid((int)v.w) / BSZ], 1);
        }
    }

    red[t] = local;
    __syncthreads();                 // also fences all LDS hist atomics
    for (int s2 = 128; s2 > 0; s2 >>= 1) {
        if (t < s2) red[t] += red[t + s2];
        __syncthreads();
    }
    if (t == 0 && red[0]) atomicAdd(&fl[1], red[0]);
    if (h[t]) atomicAdd(&bcnt[t], h[t]);
}

// ---- parallel exclusive scan of bucket counts (1 block) ----
__global__ void __launch_bounds__(256) k_bscan(const int* __restrict__ bcnt,
                                               int* __restrict__ bbase,
                                               int* __restrict__ bcur) {
    __shared__ int sb[PNB];
    int t = threadIdx.x;
    int c = bcnt[t];
    sb[t] = c;
    __syncthreads();
    for (int off = 1; off < PNB; off <<= 1) {
        int v = (t >= off) ? sb[t - off] : 0;
        __syncthreads();
        sb[t] += v;
        __syncthreads();
    }
    int ex = sb[t] - c;
    bbase[t] = ex;
    bcur[t] = ex;
    if (t == PNB - 1) bbase[PNB] = sb[t];
}

// ---- partition edges into dst-buckets, LDS counting sort per 4096-edge block ----
__global__ void __launch_bounds__(256) k_part(const int* __restrict__ edge,
                                              int i64,
                                              int* __restrict__ bcur,
                                              uint2* __restrict__ pairs) {
    __shared__ int h[PNB];
    __shared__ int excl[PNB];
    __shared__ int gbase[PNB];
    __shared__ int lcur[PNB];
    __shared__ uint2 st[EPB];
    __shared__ unsigned char binof[EPB];
    int t = threadIdx.x;
    int e0 = blockIdx.x * EPB;
    int nval = N_EDGES - e0;
    if (nval > EPB) nval = EPB;
    const uint4* e4 = (const uint4*)edge;

    h[t] = 0;
    __syncthreads();
    // count pass
    if (i64) {
        int half = nval >> 1;                       // nval always even
        for (int m = t; m < half; m += 256) {
            uint4 v = e4[(size_t)(N_EDGES / 2) + (e0 >> 1) + m];
            atomicAdd(&h[clampid((int)v.x) / BSZ], 1);
            atomicAdd(&h[clampid((int)v.z) / BSZ], 1);
        }
    } else {
        for (int k = t; k < nval; k += 256) {
            int d = clampid(rd_dst(edge, 0, e0 + k));
            atomicAdd(&h[d / BSZ], 1);
        }
    }
    __syncthreads();
    int c = h[t];
    excl[t] = c;
    __syncthreads();
    for (int off = 1; off < 256; off <<= 1) {
        int v = (t >= off) ? excl[t - off] : 0;
        __syncthreads();
        excl[t] += v;
        __syncthreads();
    }
    int myexcl = excl[t] - c;
    __syncthreads();
    excl[t] = myexcl;
    gbase[t] = (c > 0) ? atomicAdd(&bcur[t], c) : 0;
    lcur[t] = myexcl;
    __syncthreads();
    // scatter into LDS, ordered by bucket
    if (i64) {
        int half = nval >> 1;
        for (int m = t; m < half; m += 256) {
            uint4 vs = e4[(e0 >> 1) + m];
            uint4 vd = e4[(size_t)(N_EDGES / 2) + (e0 >> 1) + m];
            int s0 = clampid((int)vs.x), d0 = clampid((int)vd.x);
            int b0 = d0 / BSZ;
            int lp0 = atomicAdd(&lcur[b0], 1);
            st[lp0] = make_uint2((unsigned)s0, (unsigned)d0);
            binof[lp0] = (unsigned char)b0;
            int s1 = clampid((int)vs.z), d1 = clampid((int)vd.z);
            int b1 = d1 / BSZ;
            int lp1 = atomicAdd(&lcur[b1], 1);
            st[lp1] = make_uint2((unsigned)s1, (unsigned)d1);
            binof[lp1] = (unsigned char)b1;
        }
    } else {
        for (int k = t; k < nval; k += 256) {
            int s = clampid(rd_src(edge, 0, e0 + k));
            int d = clampid(rd_dst(edge, 0, e0 + k));
            int b = d / BSZ;
            int lp = atomicAdd(&lcur[b], 1);
            st[lp] = make_uint2((unsigned)s, (unsigned)d);
            binof[lp] = (unsigned char)b;
        }
    }
    __syncthreads();
    // flush: runs of same-bucket pairs -> contiguous global spans (coalesced)
    for (int k = t; k < nval; k += 256) {
        int b = binof[k];
        pairs[gbase[b] + (k - excl[b])] = st[k];
    }
}

// ---- fused: per-row hist -> scan -> rowptr/dis emit -> place ----
__global__ void __launch_bounds__(1024) k_build(const uint2* __restrict__ pairs,
                                                const int* __restrict__ bbase,
                                                int* __restrict__ rowptr,
                                                float* __restrict__ dis,
                                                int* __restrict__ csr) {
    __shared__ int hh[BSZ];     // per-row counts -> global cursors
    __shared__ int rt[512];     // row-total scan
    int b = blockIdx.x;
    int t = threadIdx.x;
    int base = b * BSZ;
    for (int i = t; i < BSZ; i += 1024) hh[i] = 0;
    __syncthreads();
    int beg = bbase[b], end = bbase[b + 1];
    for (int i = beg + t; i < end; i += 1024)
        atomicAdd(&hh[(int)pairs[i].y - base], 1);
    __syncthreads();
    int rtot = (t < BSZ) ? hh[t] : 0;
    if (t < 512) rt[t] = (t < BSZ) ? rtot : 0;
    __syncthreads();
    for (int off = 1; off < 512; off <<= 1) {
        int v = 0;
        if (t < 512 && t >= off) v = rt[t - off];
        __syncthreads();
        if (t < 512 && t >= off) rt[t] += v;
        __syncthreads();
    }
    if (t < BSZ) {
        int gb = beg + (rt[t] - rtot);   // global row start
        int n = base + t;
        if (n < N_NODES) {
            dis[n] = (rtot > 0) ? rsqrtf((float)rtot) : 0.0f;
            rowptr[n] = gb;
            if (n == N_NODES - 1) rowptr[N_NODES] = N_EDGES;
        }
        hh[t] = gb;                       // -> global cursor
    }
    __syncthreads();
    for (int i = beg + t; i < end; i += 1024) {
        uint2 p = pairs[i];
        int pos = atomicAdd(&hh[(int)p.y - base], 1);
        csr[pos] = (int)p.x;
    }
}

// out (fp32, = d_out) = emb; Y0 = bf16(dis ⊙ emb), ROW-MAJOR.
// 8 elems per thread, f32x4 loads/stores on the fp32 fast path.
__global__ void __launch_bounds__(256) k_init(const void* __restrict__ emb,
                                              const int* __restrict__ fl,
                                              const float* __restrict__ dis,
                                              float* __restrict__ out,
                                              bf16* __restrict__ Y) {
    int idx = blockIdx.x * 256 + threadIdx.x;      // 800K threads
    if (idx >= ND / 8) return;
    int n = idx >> 3;
    float dn = dis[n];
    float f[8];
    if (fl[1] < (ND / 128)) {                      // bf16 emb (sampled census)
        const bf16* eb = (const bf16*)emb + (size_t)idx * 8;
        for (int k = 0; k < 8; k++) f[k] = __bfloat162float(eb[k]);
    } else {
        const f32x4* e4 = (const f32x4*)emb + (size_t)idx * 2;
        f32x4 a = e4[0], b = e4[1];
        f[0] = a.x; f[1] = a.y; f[2] = a.z; f[3] = a.w;
        f[4] = b.x; f[5] = b.y; f[6] = b.z; f[7] = b.w;
    }
    f32x4* o4 = (f32x4*)out + (size_t)idx * 2;
    f32x4 oa, ob;
    oa.x = f[0]; oa.y = f[1]; oa.z = f[2]; oa.w = f[3];
    ob.x = f[4]; ob.y = f[5]; ob.z = f[6]; ob.w = f[7];
    o4[0] = oa; o4[1] = ob;
    u16x4* yp = (u16x4*)Y + (size_t)idx * 2;
    u16x4 y0, y1;
    bf16 tb;
    tb = __float2bfloat16(dn * f[0]); y0.x = *(unsigned short*)&tb;
    tb = __float2bfloat16(dn * f[1]); y0.y = *(unsigned short*)&tb;
    tb = __float2bfloat16(dn * f[2]); y0.z = *(unsigned short*)&tb;
    tb = __float2bfloat16(dn * f[3]); y0.w = *(unsigned short*)&tb;
    tb = __float2bfloat16(dn * f[4]); y1.x = *(unsigned short*)&tb;
    tb = __float2bfloat16(dn * f[5]); y1.y = *(unsigned short*)&tb;
    tb = __float2bfloat16(dn * f[6]); y1.z = *(unsigned short*)&tb;
    tb = __float2bfloat16(dn * f[7]); y1.w = *(unsigned short*)&tb;
    yp[0] = y0; yp[1] = y1;
}

#define GATHER4(SRC)                                                     \
    {                                                                    \
        uint2 v = *(const uint2*)(Yu + (size_t)(SRC) * 32 + l16 * 2);    \
        a0 += __uint_as_float(v.x << 16);                                \
        a1 += __uint_as_float(v.x & 0xffff0000u);                        \
        a2 += __uint_as_float(v.y << 16);                                \
        a3 += __uint_as_float(v.y & 0xffff0000u);                        \
    }

// wave-per-row whole-row SpMM (round-3 structure, the measured fastest):
// 16 lanes per edge (uint2 = 4 bf16), 4 edge quarters, 16-edge main loop
// => 4 csr + 4 gathers in flight per wave. Y served by L2/L3 (12.8MB).
__global__ void __launch_bounds__(256) k_spmm(
        const int* __restrict__ rowptr, const int* __restrict__ csr,
        const float* __restrict__ dis, const bf16* __restrict__ Yin,
        float* __restrict__ out, bf16* __restrict__ Yout, int last) {
    int wave = threadIdx.x >> 6;
    int lane = threadIdx.x & 63;
    int q    = lane >> 4;        // edge quarter
    int l16  = lane & 15;        // col group: cols 4*l16 .. 4*l16+3
    int n = blockIdx.x * 4 + wave;
    if (n >= N_NODES) return;
    int beg = rowptr[n];
    int end = rowptr[n + 1];
    const unsigned* Yu = (const unsigned*)Yin;   // 2 bf16 per word
    float a0 = 0.f, a1 = 0.f, a2 = 0.f, a3 = 0.f;
    int j = beg;
    for (; j + 16 <= end; j += 16) {
        int s0 = csr[j + q];
        int s1 = csr[j + 4 + q];
        int s2 = csr[j + 8 + q];
        int s3 = csr[j + 12 + q];
        GATHER4(s0);
        GATHER4(s1);
        GATHER4(s2);
        GATHER4(s3);
    }
    for (; j + 8 <= end; j += 8) {
        int s0 = csr[j + q];
        int s1 = csr[j + 4 + q];
        GATHER4(s0);
        GATHER4(s1);
    }
    if (j + q < end)     { int sv = csr[j + q];     GATHER4(sv); }
    if (j + 4 + q < end) { int sv = csr[j + 4 + q]; GATHER4(sv); }
    // combine the 4 quarters: lanes l, l^16, l^32, l^48 hold the same cols
    a0 += __shfl_xor(a0, 16); a0 += __shfl_xor(a0, 32);
    a1 += __shfl_xor(a1, 16); a1 += __shfl_xor(a1, 32);
    a2 += __shfl_xor(a2, 16); a2 += __shfl_xor(a2, 32);
    a3 += __shfl_xor(a3, 16); a3 += __shfl_xor(a3, 32);
    if (lane < 16) {
        float dn = dis[n];
        float x0 = dn * a0, x1 = dn * a1, x2 = dn * a2, x3 = dn * a3;
        int i4 = n * 16 + l16;                 // f32x4 index into out
        f32x4 o = __builtin_nontemporal_load((const f32x4*)out + i4);
        if (last) {
            o.x = (o.x + x0) * 0.25f;
            o.y = (o.y + x1) * 0.25f;
            o.z = (o.z + x2) * 0.25f;
            o.w = (o.w + x3) * 0.25f;
            __builtin_nontemporal_store(o, (f32x4*)out + i4);
        } else {
            o.x += x0; o.y += x1; o.z += x2; o.w += x3;
            __builtin_nontemporal_store(o, (f32x4*)out + i4);
            bf16 t0 = __float2bfloat16(dn * x0);
            bf16 t1 = __float2bfloat16(dn * x1);
            bf16 t2 = __float2bfloat16(dn * x2);
            bf16 t3 = __float2bfloat16(dn * x3);
            u16x4 yv;
            yv.x = *(unsigned short*)&t0;
            yv.y = *(unsigned short*)&t1;
            yv.z = *(unsigned short*)&t2;
            yv.w = *(unsigned short*)&t3;
            __builtin_nontemporal_store(yv, (u16x4*)Yout + (size_t)n * 16 + l16);
        }
    }
}

__global__ void k_fill42(float* __restrict__ o) {
    int i = blockIdx.x * blockDim.x + threadIdx.x;
    if (i < ND) o[i] = 42.0f;   // signature: ws too small for CSR layout
}

extern "C" void kernel_launch(void* const* d_in, const int* in_sizes, int n_in,
                              void* d_out, int out_size, void* d_ws, size_t ws_size,
                              hipStream_t stream) {
    const void* emb = d_in[0];
    const int* edge = (const int*)d_in[1];
    float* out = (float*)d_out;

    // host-side dtype resolution: int64 edge buffer = 2*E*8 bytes
    const long long i64_bytes = 2LL * N_EDGES * 8;
    int i64 = (in_sizes[1] >= (int)i64_bytes) ? 1 : 0;

    const int B = 256;
    const int gND = (ND + B - 1) / B;           // 25000
    const int gI  = (ND / 8 + B - 1) / B;       // 3125
    const int gP  = (N_EDGES + EPB - 1) / EPB;  // 782 partition blocks
    const int gW  = (N_NODES + 3) / 4;          // 25000 wave-per-row blocks

    char* ws = (char*)d_ws;
    int* fl = (int*)ws;
    size_t off = 256;
    const size_t off_dis    = off;  off += (size_t)N_NODES * 4;
    const size_t off_rowptr = off;  off += (size_t)(N_NODES + 1) * 4 + 4;
    const size_t off_bcnt   = off;  off += 1024;
    const size_t off_bbase  = off;  off += 1056;
    const size_t off_bcur   = off;  off += 1024;
    const size_t off_csr    = off;  off += (size_t)N_EDGES * 4;
    const size_t off_Y0     = off;  off += (size_t)ND * 2;
    const size_t off_Y1     = off;  off += (size_t)ND * 2;
    const size_t need = off;                    // ~39.2 MB

    if (ws_size < need) {
        k_fill42<<<gND, B, 0, stream>>>(out);
        return;
    }

    float* dis    = (float*)(ws + off_dis);
    int*   rowptr = (int*)(ws + off_rowptr);
    int*   bcnt   = (int*)(ws + off_bcnt);
    int*   bbase  = (int*)(ws + off_bbase);
    int*   bcur   = (int*)(ws + off_bcur);
    int*   csr    = (int*)(ws + off_csr);
    uint2* pairs  = (uint2*)(ws + off_Y0);      // 25.6MB, reuses Y0+Y1 (dead until k_init)
    bf16*  Y0     = (bf16*)(ws + off_Y0);
    bf16*  Y1     = (bf16*)(ws + off_Y1);

    k_flags0<<<1, 256, 0, stream>>>(fl, bcnt);
    k_scanb<<<512, B, 0, stream>>>(edge, (const uint4*)emb, i64, fl, bcnt);

    // bucketed CSR build
    k_bscan<<<1, 256, 0, stream>>>(bcnt, bbase, bcur);
    k_part<<<gP, B, 0, stream>>>(edge, i64, bcur, pairs);
    k_build<<<PNB, 1024, 0, stream>>>(pairs, bbase, rowptr, dis, csr);

    k_init<<<gI, B, 0, stream>>>(emb, fl, dis, out, Y0);

    k_spmm<<<gW, B, 0, stream>>>(rowptr, csr, dis, Y0, out, Y1, 0);
    k_spmm<<<gW, B, 0, stream>>>(rowptr, csr, dis, Y1, out, Y0, 0);
    k_spmm<<<gW, B, 0, stream>>>(rowptr, csr, dis, Y0, out, Y1, 1);
}

// Round 11
// 445.320 us; speedup vs baseline: 2.5788x; 1.0012x over previous
//
#include <hip/hip_runtime.h>
#include <hip/hip_bf16.h>

typedef __hip_bfloat16 bf16;
typedef float          f32x4 __attribute__((ext_vector_type(4)));
typedef unsigned short u16x4 __attribute__((ext_vector_type(4)));

#define N_NODES  100000
#define EMBED    64
#define N_EDGES  3200000
#define ND       6400000
#define N_LAYERS 3

// bucketed CSR build
#define PNB  256            // number of dst buckets
#define BSZ  391            // nodes per bucket (256*391 = 100096 >= N_NODES)
#define EPB  4096           // edges per partition block (even in every block)

// packed pair: (row_in_bucket << 17) | src   (src < 2^17, row < 2^9)
#define PK(r, s)  (((unsigned)(r) << 17) | (unsigned)(s))
#define PK_R(p)   ((int)((p) >> 17))
#define PK_S(p)   ((int)((p) & 0x1FFFFu))

// flags: [1] emb_outl census (over first ND/8 u16s; threshold ND/128)

__global__ void k_flags0(int* f, int* bcnt) {
    int t = threadIdx.x;
    if (t < 16) f[t] = 0;
    bcnt[t] = 0;
}

__device__ __forceinline__ int rd_src(const int* e, int i64, int k) {
    return i64 ? e[2 * k] : e[k];
}
__device__ __forceinline__ int rd_dst(const int* e, int i64, int k) {
    return i64 ? e[2 * (N_EDGES + k)] : e[N_EDGES + k];
}
__device__ __forceinline__ int clampid(int v) {
    return (v < 0) ? 0 : ((v >= N_NODES) ? (N_NODES - 1) : v);
}

// fused: emb census (sampled, block-reduced) + coarse dst-bucket histogram.
__global__ void __launch_bounds__(256) k_scanb(const int* __restrict__ edge,
                                               const uint4* __restrict__ emb4,
                                               int i64, int* __restrict__ fl,
                                               int* __restrict__ bcnt) {
    __shared__ int h[PNB];
    __shared__ int red[256];
    int t = threadIdx.x;
    int gid = blockIdx.x * 256 + t;
    int step = gridDim.x * 256;
    h[t] = 0;
    __syncthreads();

    // emb census: first ND/8 u16s as uint4 (8 u16 each)
    int local = 0;
    const int NV_M = ND / 64;                  // 100,000 vecs
#define CEN8(v)                                                          \
    {                                                                    \
        unsigned b;                                                      \
        b = ((v).x >> 8)  & 0x7f; if (b < 0x2e || b > 0x41) local++;     \
        b = ((v).x >> 24) & 0x7f; if (b < 0x2e || b > 0x41) local++;     \
        b = ((v).y >> 8)  & 0x7f; if (b < 0x2e || b > 0x41) local++;     \
        b = ((v).y >> 24) & 0x7f; if (b < 0x2e || b > 0x41) local++;     \
        b = ((v).z >> 8)  & 0x7f; if (b < 0x2e || b > 0x41) local++;     \
        b = ((v).z >> 24) & 0x7f; if (b < 0x2e || b > 0x41) local++;     \
        b = ((v).w >> 8)  & 0x7f; if (b < 0x2e || b > 0x41) local++;     \
        b = ((v).w >> 24) & 0x7f; if (b < 0x2e || b > 0x41) local++;     \
    }
    for (int i = gid; i < NV_M; i += step) {
        uint4 v = emb4[i];
        CEN8(v);
    }
#undef CEN8

    // dst-bucket histogram (uint4 loads)
    const uint4* e4 = (const uint4*)edge;
    if (i64) {
        const int base = N_EDGES / 2;          // dst half starts at word 2*N_EDGES
        const int nv   = N_EDGES / 2;          // 2 edges per vec (x,z)
        for (int k = gid; k < nv; k += step) {
            uint4 v = e4[base + k];
            atomicAdd(&h[clampid((int)v.x) / BSZ], 1);
            atomicAdd(&h[clampid((int)v.z) / BSZ], 1);
        }
    } else {
        const int base = N_EDGES / 4;          // dst half at word N_EDGES
        const int nv   = N_EDGES / 4;          // 4 edges per vec
        for (int k = gid; k < nv; k += step) {
            uint4 v = e4[base + k];
            atomicAdd(&h[clampid((int)v.x) / BSZ], 1);
            atomicAdd(&h[clampid((int)v.y) / BSZ], 1);
            atomicAdd(&h[clampid((int)v.z) / BSZ], 1);
            atomicAdd(&h[clampid((int)v.w) / BSZ], 1);
        }
    }

    red[t] = local;
    __syncthreads();                 // also fences all LDS hist atomics
    for (int s2 = 128; s2 > 0; s2 >>= 1) {
        if (t < s2) red[t] += red[t + s2];
        __syncthreads();
    }
    if (t == 0 && red[0]) atomicAdd(&fl[1], red[0]);
    if (h[t]) atomicAdd(&bcnt[t], h[t]);
}

// ---- parallel exclusive scan of bucket counts (1 block) ----
__global__ void __launch_bounds__(256) k_bscan(const int* __restrict__ bcnt,
                                               int* __restrict__ bbase,
                                               int* __restrict__ bcur) {
    __shared__ int sb[PNB];
    int t = threadIdx.x;
    int c = bcnt[t];
    sb[t] = c;
    __syncthreads();
    for (int off = 1; off < PNB; off <<= 1) {
        int v = (t >= off) ? sb[t - off] : 0;
        __syncthreads();
        sb[t] += v;
        __syncthreads();
    }
    int ex = sb[t] - c;
    bbase[t] = ex;
    bcur[t] = ex;
    if (t == PNB - 1) bbase[PNB] = sb[t];
}

// ---- partition edges into dst-buckets, LDS counting sort per 4096-edge block.
// Emits PACKED u32 pairs (row-in-bucket | src). LDS 24KB (was 40KB). ----
__global__ void __launch_bounds__(256) k_part(const int* __restrict__ edge,
                                              int i64,
                                              int* __restrict__ bcur,
                                              unsigned* __restrict__ pairs) {
    __shared__ int h[PNB];
    __shared__ int excl[PNB];
    __shared__ int gbase[PNB];
    __shared__ int lcur[PNB];
    __shared__ unsigned st[EPB];
    __shared__ unsigned char binof[EPB];
    int t = threadIdx.x;
    int e0 = blockIdx.x * EPB;
    int nval = N_EDGES - e0;
    if (nval > EPB) nval = EPB;
    const uint4* e4 = (const uint4*)edge;

    h[t] = 0;
    __syncthreads();
    // count pass
    if (i64) {
        int half = nval >> 1;                       // nval always even
        for (int m = t; m < half; m += 256) {
            uint4 v = e4[(size_t)(N_EDGES / 2) + (e0 >> 1) + m];
            atomicAdd(&h[clampid((int)v.x) / BSZ], 1);
            atomicAdd(&h[clampid((int)v.z) / BSZ], 1);
        }
    } else {
        for (int k = t; k < nval; k += 256) {
            int d = clampid(rd_dst(edge, 0, e0 + k));
            atomicAdd(&h[d / BSZ], 1);
        }
    }
    __syncthreads();
    int c = h[t];
    excl[t] = c;
    __syncthreads();
    for (int off = 1; off < 256; off <<= 1) {
        int v = (t >= off) ? excl[t - off] : 0;
        __syncthreads();
        excl[t] += v;
        __syncthreads();
    }
    int myexcl = excl[t] - c;
    __syncthreads();
    excl[t] = myexcl;
    gbase[t] = (c > 0) ? atomicAdd(&bcur[t], c) : 0;
    lcur[t] = myexcl;
    __syncthreads();
    // scatter into LDS, ordered by bucket
    if (i64) {
        int half = nval >> 1;
        for (int m = t; m < half; m += 256) {
            uint4 vs = e4[(e0 >> 1) + m];
            uint4 vd = e4[(size_t)(N_EDGES / 2) + (e0 >> 1) + m];
            int s0 = clampid((int)vs.x), d0 = clampid((int)vd.x);
            int b0 = d0 / BSZ;
            int lp0 = atomicAdd(&lcur[b0], 1);
            st[lp0] = PK(d0 - b0 * BSZ, s0);
            binof[lp0] = (unsigned char)b0;
            int s1 = clampid((int)vs.z), d1 = clampid((int)vd.z);
            int b1 = d1 / BSZ;
            int lp1 = atomicAdd(&lcur[b1], 1);
            st[lp1] = PK(d1 - b1 * BSZ, s1);
            binof[lp1] = (unsigned char)b1;
        }
    } else {
        for (int k = t; k < nval; k += 256) {
            int s = clampid(rd_src(edge, 0, e0 + k));
            int d = clampid(rd_dst(edge, 0, e0 + k));
            int b = d / BSZ;
            int lp = atomicAdd(&lcur[b], 1);
            st[lp] = PK(d - b * BSZ, s);
            binof[lp] = (unsigned char)b;
        }
    }
    __syncthreads();
    // flush: runs of same-bucket pairs -> contiguous global spans (coalesced)
    for (int k = t; k < nval; k += 256) {
        int b = binof[k];
        pairs[gbase[b] + (k - excl[b])] = st[k];
    }
}

// ---- fused: per-row hist -> scan -> rowptr/dis emit -> place (packed pairs) ----
__global__ void __launch_bounds__(1024) k_build(const unsigned* __restrict__ pairs,
                                                const int* __restrict__ bbase,
                                                int* __restrict__ rowptr,
                                                float* __restrict__ dis,
                                                int* __restrict__ csr) {
    __shared__ int hh[BSZ];     // per-row counts -> global cursors
    __shared__ int rt[512];     // row-total scan
    int b = blockIdx.x;
    int t = threadIdx.x;
    int base = b * BSZ;
    for (int i = t; i < BSZ; i += 1024) hh[i] = 0;
    __syncthreads();
    int beg = bbase[b], end = bbase[b + 1];
    for (int i = beg + t; i < end; i += 1024)
        atomicAdd(&hh[PK_R(pairs[i])], 1);
    __syncthreads();
    int rtot = (t < BSZ) ? hh[t] : 0;
    if (t < 512) rt[t] = (t < BSZ) ? rtot : 0;
    __syncthreads();
    for (int off = 1; off < 512; off <<= 1) {
        int v = 0;
        if (t < 512 && t >= off) v = rt[t - off];
        __syncthreads();
        if (t < 512 && t >= off) rt[t] += v;
        __syncthreads();
    }
    if (t < BSZ) {
        int gb = beg + (rt[t] - rtot);   // global row start
        int n = base + t;
        if (n < N_NODES) {
            dis[n] = (rtot > 0) ? rsqrtf((float)rtot) : 0.0f;
            rowptr[n] = gb;
            if (n == N_NODES - 1) rowptr[N_NODES] = N_EDGES;
        }
        hh[t] = gb;                       // -> global cursor
    }
    __syncthreads();
    for (int i = beg + t; i < end; i += 1024) {
        unsigned p = pairs[i];
        int pos = atomicAdd(&hh[PK_R(p)], 1);
        csr[pos] = PK_S(p);
    }
}

// Y0 = bf16(dis ⊙ emb), ROW-MAJOR. On the fp32 path `out` is NOT written
// (first spmm reads emb directly); on the bf16 path out = emb (decoded).
__global__ void __launch_bounds__(256) k_init(const void* __restrict__ emb,
                                              const int* __restrict__ fl,
                                              const float* __restrict__ dis,
                                              float* __restrict__ out,
                                              bf16* __restrict__ Y) {
    int idx = blockIdx.x * 256 + threadIdx.x;      // 800K threads
    if (idx >= ND / 8) return;
    int n = idx >> 3;
    float dn = dis[n];
    float f[8];
    if (fl[1] < (ND / 128)) {                      // bf16 emb (sampled census)
        const bf16* eb = (const bf16*)emb + (size_t)idx * 8;
        for (int k = 0; k < 8; k++) f[k] = __bfloat162float(eb[k]);
        f32x4* o4 = (f32x4*)out + (size_t)idx * 2;
        f32x4 oa, ob;
        oa.x = f[0]; oa.y = f[1]; oa.z = f[2]; oa.w = f[3];
        ob.x = f[4]; ob.y = f[5]; ob.z = f[6]; ob.w = f[7];
        o4[0] = oa; o4[1] = ob;
    } else {
        const f32x4* e4 = (const f32x4*)emb + (size_t)idx * 2;
        f32x4 a = e4[0], b = e4[1];
        f[0] = a.x; f[1] = a.y; f[2] = a.z; f[3] = a.w;
        f[4] = b.x; f[5] = b.y; f[6] = b.z; f[7] = b.w;
    }
    u16x4* yp = (u16x4*)Y + (size_t)idx * 2;
    u16x4 y0, y1;
    bf16 tb;
    tb = __float2bfloat16(dn * f[0]); y0.x = *(unsigned short*)&tb;
    tb = __float2bfloat16(dn * f[1]); y0.y = *(unsigned short*)&tb;
    tb = __float2bfloat16(dn * f[2]); y0.z = *(unsigned short*)&tb;
    tb = __float2bfloat16(dn * f[3]); y0.w = *(unsigned short*)&tb;
    tb = __float2bfloat16(dn * f[4]); y1.x = *(unsigned short*)&tb;
    tb = __float2bfloat16(dn * f[5]); y1.y = *(unsigned short*)&tb;
    tb = __float2bfloat16(dn * f[6]); y1.z = *(unsigned short*)&tb;
    tb = __float2bfloat16(dn * f[7]); y1.w = *(unsigned short*)&tb;
    yp[0] = y0; yp[1] = y1;
}

#define GATHER4(SRC)                                                     \
    {                                                                    \
        uint2 v = *(const uint2*)(Yu + (size_t)(SRC) * 32 + l16 * 2);    \
        a0 += __uint_as_float(v.x << 16);                                \
        a1 += __uint_as_float(v.x & 0xffff0000u);                        \
        a2 += __uint_as_float(v.y << 16);                                \
        a3 += __uint_as_float(v.y & 0xffff0000u);                        \
    }

// wave-per-row whole-row SpMM (measured-fastest structure, at the empirical
// scattered-gather ceiling ~95us/layer). For the FIRST layer on the fp32
// path, the prior-accumulator stream is read from emb directly (fl-gated).
__global__ void __launch_bounds__(256) k_spmm(
        const int* __restrict__ rowptr, const int* __restrict__ csr,
        const float* __restrict__ dis, const bf16* __restrict__ Yin,
        const float* __restrict__ emb, const int* __restrict__ fl,
        float* __restrict__ out, bf16* __restrict__ Yout, int first, int last) {
    int wave = threadIdx.x >> 6;
    int lane = threadIdx.x & 63;
    int q    = lane >> 4;        // edge quarter
    int l16  = lane & 15;        // col group: cols 4*l16 .. 4*l16+3
    int n = blockIdx.x * 4 + wave;
    if (n >= N_NODES) return;
    int beg = rowptr[n];
    int end = rowptr[n + 1];
    const unsigned* Yu = (const unsigned*)Yin;   // 2 bf16 per word
    float a0 = 0.f, a1 = 0.f, a2 = 0.f, a3 = 0.f;
    int j = beg;
    for (; j + 16 <= end; j += 16) {
        int s0 = csr[j + q];
        int s1 = csr[j + 4 + q];
        int s2 = csr[j + 8 + q];
        int s3 = csr[j + 12 + q];
        GATHER4(s0);
        GATHER4(s1);
        GATHER4(s2);
        GATHER4(s3);
    }
    for (; j + 8 <= end; j += 8) {
        int s0 = csr[j + q];
        int s1 = csr[j + 4 + q];
        GATHER4(s0);
        GATHER4(s1);
    }
    if (j + q < end)     { int sv = csr[j + q];     GATHER4(sv); }
    if (j + 4 + q < end) { int sv = csr[j + 4 + q]; GATHER4(sv); }
    // combine the 4 quarters: lanes l, l^16, l^32, l^48 hold the same cols
    a0 += __shfl_xor(a0, 16); a0 += __shfl_xor(a0, 32);
    a1 += __shfl_xor(a1, 16); a1 += __shfl_xor(a1, 32);
    a2 += __shfl_xor(a2, 16); a2 += __shfl_xor(a2, 32);
    a3 += __shfl_xor(a3, 16); a3 += __shfl_xor(a3, 32);
    if (lane < 16) {
        float dn = dis[n];
        float x0 = dn * a0, x1 = dn * a1, x2 = dn * a2, x3 = dn * a3;
        int i4 = n * 16 + l16;                 // f32x4 index
        const f32x4* ip = (first && fl[1] >= (ND / 128))
                              ? (const f32x4*)emb : (const f32x4*)out;
        f32x4 o = __builtin_nontemporal_load(ip + i4);
        if (last) {
            o.x = (o.x + x0) * 0.25f;
            o.y = (o.y + x1) * 0.25f;
            o.z = (o.z + x2) * 0.25f;
            o.w = (o.w + x3) * 0.25f;
            __builtin_nontemporal_store(o, (f32x4*)out + i4);
        } else {
            o.x += x0; o.y += x1; o.z += x2; o.w += x3;
            __builtin_nontemporal_store(o, (f32x4*)out + i4);
            bf16 t0 = __float2bfloat16(dn * x0);
            bf16 t1 = __float2bfloat16(dn * x1);
            bf16 t2 = __float2bfloat16(dn * x2);
            bf16 t3 = __float2bfloat16(dn * x3);
            u16x4 yv;
            yv.x = *(unsigned short*)&t0;
            yv.y = *(unsigned short*)&t1;
            yv.z = *(unsigned short*)&t2;
            yv.w = *(unsigned short*)&t3;
            __builtin_nontemporal_store(yv, (u16x4*)Yout + (size_t)n * 16 + l16);
        }
    }
}

__global__ void k_fill42(float* __restrict__ o) {
    int i = blockIdx.x * blockDim.x + threadIdx.x;
    if (i < ND) o[i] = 42.0f;   // signature: ws too small for CSR layout
}

extern "C" void kernel_launch(void* const* d_in, const int* in_sizes, int n_in,
                              void* d_out, int out_size, void* d_ws, size_t ws_size,
                              hipStream_t stream) {
    const void* emb = d_in[0];
    const int* edge = (const int*)d_in[1];
    float* out = (float*)d_out;

    // host-side dtype resolution: int64 edge buffer = 2*E*8 bytes
    const long long i64_bytes = 2LL * N_EDGES * 8;
    int i64 = (in_sizes[1] >= (int)i64_bytes) ? 1 : 0;

    const int B = 256;
    const int gND = (ND + B - 1) / B;           // 25000
    const int gI  = (ND / 8 + B - 1) / B;       // 3125
    const int gP  = (N_EDGES + EPB - 1) / EPB;  // 782 partition blocks
    const int gW  = (N_NODES + 3) / 4;          // 25000 wave-per-row blocks

    char* ws = (char*)d_ws;
    int* fl = (int*)ws;
    size_t off = 256;
    const size_t off_dis    = off;  off += (size_t)N_NODES * 4;
    const size_t off_rowptr = off;  off += (size_t)(N_NODES + 1) * 4 + 4;
    const size_t off_bcnt   = off;  off += 1024;
    const size_t off_bbase  = off;  off += 1056;
    const size_t off_bcur   = off;  off += 1024;
    const size_t off_csr    = off;  off += (size_t)N_EDGES * 4;
    const size_t off_Y0     = off;  off += (size_t)ND * 2;
    const size_t off_Y1     = off;  off += (size_t)ND * 2;
    const size_t need = off;                    // ~39.2 MB

    if (ws_size < need) {
        k_fill42<<<gND, B, 0, stream>>>(out);
        return;
    }

    float*    dis    = (float*)(ws + off_dis);
    int*      rowptr = (int*)(ws + off_rowptr);
    int*      bcnt   = (int*)(ws + off_bcnt);
    int*      bbase  = (int*)(ws + off_bbase);
    int*      bcur   = (int*)(ws + off_bcur);
    int*      csr    = (int*)(ws + off_csr);
    unsigned* pairs  = (unsigned*)(ws + off_Y0); // 12.8MB packed, reuses Y0 (dead until k_init)
    bf16*     Y0     = (bf16*)(ws + off_Y0);
    bf16*     Y1     = (bf16*)(ws + off_Y1);

    k_flags0<<<1, 256, 0, stream>>>(fl, bcnt);
    k_scanb<<<512, B, 0, stream>>>(edge, (const uint4*)emb, i64, fl, bcnt);

    // bucketed CSR build (packed pairs)
    k_bscan<<<1, 256, 0, stream>>>(bcnt, bbase, bcur);
    k_part<<<gP, B, 0, stream>>>(edge, i64, bcur, pairs);
    k_build<<<PNB, 1024, 0, stream>>>(pairs, bbase, rowptr, dis, csr);

    k_init<<<gI, B, 0, stream>>>(emb, fl, dis, out, Y0);

    k_spmm<<<gW, B, 0, stream>>>(rowptr, csr, dis, Y0, (const float*)emb, fl, out, Y1, 1, 0);
    k_spmm<<<gW, B, 0, stream>>>(rowptr, csr, dis, Y1, (const float*)emb, fl, out, Y0, 0, 0);
    k_spmm<<<gW, B, 0, stream>>>(rowptr, csr, dis, Y0, (const float*)emb, fl, out, Y1, 0, 1);
}